// Round 1
// baseline (1085.430 us; speedup 1.0000x reference)
//
#include <hip/hip_runtime.h>
#include <hip/hip_bf16.h>

#define B_ 2
#define H_ 4
#define T_ 2048
#define NH_ 8192
#define D_ 256

typedef __attribute__((ext_vector_type(4))) float f32x4;
typedef __attribute__((ext_vector_type(8))) short bf16x8;
typedef __attribute__((ext_vector_type(4))) int i32x4;

__device__ __forceinline__ unsigned short f2bf(float f) {
    union { float f; unsigned u; } v;
    v.f = f;
    unsigned u = v.u;
    unsigned r = u + 0x7FFFu + ((u >> 16) & 1u);   // RNE
    return (unsigned short)(r >> 16);
}

// ---------------------------------------------------------------------------
// Kernel 1: RoPE + cast to bf16 for Q and K (shared trig per (t,n) pair)
// freq[pair p] = 2^(-p/256) / (2*pi)   (theta=2^16, NH=8192 exactly)
// ---------------------------------------------------------------------------
__global__ __launch_bounds__(256) void rope_cast_kernel(
    const float* __restrict__ Q, const float* __restrict__ K,
    unsigned short* __restrict__ Qb, unsigned short* __restrict__ Kb,
    int bh0)
{
    const long gid = (long)blockIdx.x * 256 + threadIdx.x;  // one 8-elem group
    const int ng = NH_ / 8;
    const int n8 = (int)(gid % ng) * 8;
    const long row = gid / ng;              // lbh*T + t
    const int t = (int)(row % T_);
    const int lbh = (int)(row / T_);

    const long in_off  = ((long)(bh0 + lbh) * T_ + t) * NH_ + n8;
    const long out_off = ((long)lbh * T_ + t) * NH_ + n8;

    float4 qa = *(const float4*)(Q + in_off);
    float4 qb4 = *(const float4*)(Q + in_off + 4);
    float4 ka = *(const float4*)(K + in_off);
    float4 kb4 = *(const float4*)(K + in_off + 4);
    float qv[8] = {qa.x, qa.y, qa.z, qa.w, qb4.x, qb4.y, qb4.z, qb4.w};
    float kv[8] = {ka.x, ka.y, ka.z, ka.w, kb4.x, kb4.y, kb4.z, kb4.w};

    union { i32x4 v; unsigned short u[8]; } qo, ko;
    const int p0 = n8 >> 1;
    const float tf = (float)t;
#pragma unroll
    for (int j = 0; j < 4; ++j) {
        float freq = exp2f(-(float)(p0 + j) * (1.0f / 256.0f)) * 0.15915494309189535f;
        float phase = tf * freq;
        float r = phase - floorf(phase);
        float ph = r * 6.283185307179586f;
        float c = __cosf(ph);
        float s = __sinf(ph);
        float qe = qv[2 * j], qodd = qv[2 * j + 1];
        float ke = kv[2 * j], kodd = kv[2 * j + 1];
        qo.u[2 * j]     = f2bf(qe * c - qodd * s);
        qo.u[2 * j + 1] = f2bf(qodd * c + qe * s);
        ko.u[2 * j]     = f2bf(ke * c - kodd * s);
        ko.u[2 * j + 1] = f2bf(kodd * c + ke * s);
    }
    *(i32x4*)(Qb + out_off) = qo.v;
    *(i32x4*)(Kb + out_off) = ko.v;
}

// ---------------------------------------------------------------------------
// Kernel 2: V [B,T,D] fp32 -> Vt [B,D,T] bf16 (transposed cast, LDS tiled)
// ---------------------------------------------------------------------------
__global__ __launch_bounds__(256) void vcast_kernel(
    const float* __restrict__ V, unsigned short* __restrict__ Vt)
{
    __shared__ unsigned short tile[64][72];
    const int t0 = blockIdx.x * 64;
    const int d0 = blockIdx.y * 64;
    const int b = blockIdx.z;
    const int tid = threadIdx.x;
#pragma unroll
    for (int rr = 0; rr < 16; ++rr) {
        int tl = rr * 4 + (tid >> 6);
        int dl = tid & 63;
        float v = V[((long)b * T_ + (t0 + tl)) * D_ + d0 + dl];
        tile[dl][tl] = f2bf(v);
    }
    __syncthreads();
#pragma unroll
    for (int rr = 0; rr < 16; ++rr) {
        int dl = rr * 4 + (tid >> 6);
        int tl = tid & 63;
        Vt[((long)b * D_ + (d0 + dl)) * T_ + t0 + tl] = tile[dl][tl];
    }
}

// ---------------------------------------------------------------------------
// Shared GEMM core helpers (m97 structure: 128x128 tile, 4 waves, BK=32,
// 16x16x32 bf16 MFMA, double-buffered global_load_lds width 16)
// ---------------------------------------------------------------------------
__device__ __forceinline__ void stage_tile(const unsigned short* g, long ldk,
                                           unsigned short* l, int tid)
{
    const int row = tid >> 2;            // 0..63
    const int col = (tid & 3) << 3;      // 0,8,16,24
    const unsigned short* g0 = g + (long)row * ldk + col;
    const unsigned short* g1 = g0 + 64 * ldk;
    unsigned short* l0 = l + tid * 8;
    unsigned short* l1 = l0 + 2048;      // rows 64..127
    __builtin_amdgcn_global_load_lds((const __attribute__((address_space(1))) void*)g0,
                                     (__attribute__((address_space(3))) void*)l0, 16, 0, 0);
    __builtin_amdgcn_global_load_lds((const __attribute__((address_space(1))) void*)g1,
                                     (__attribute__((address_space(3))) void*)l1, 16, 0, 0);
}

#define GEMM_CORE(A_PTR, B_PTR, LDK, KT)                                        \
    const int tid = threadIdx.x;                                                \
    const int lane = tid & 63;                                                  \
    const int wid = tid >> 6;                                                   \
    const int wr = wid >> 1;                                                    \
    const int wc = wid & 1;                                                     \
    f32x4 acc[4][4];                                                            \
    _Pragma("unroll") for (int m = 0; m < 4; ++m)                               \
        _Pragma("unroll") for (int n = 0; n < 4; ++n)                           \
            acc[m][n] = (f32x4){0.f, 0.f, 0.f, 0.f};                            \
    const int rofs = lane & 15;                                                 \
    const int kofs = (lane >> 4) * 8;                                           \
    stage_tile((A_PTR), (LDK), &As[0][0][0], tid);                              \
    stage_tile((B_PTR), (LDK), &Bs[0][0][0], tid);                              \
    int cur = 0;                                                                \
    for (int kt = 0; kt < (KT); ++kt) {                                         \
        __syncthreads();                                                        \
        if (kt + 1 < (KT)) {                                                    \
            stage_tile((A_PTR) + (long)(kt + 1) * 32, (LDK), &As[cur ^ 1][0][0], tid); \
            stage_tile((B_PTR) + (long)(kt + 1) * 32, (LDK), &Bs[cur ^ 1][0][0], tid); \
        }                                                                       \
        bf16x8 af[4], bfr[4];                                                   \
        _Pragma("unroll") for (int m = 0; m < 4; ++m)                           \
            af[m] = *(const bf16x8*)&As[cur][wr * 64 + m * 16 + rofs][kofs];    \
        _Pragma("unroll") for (int n = 0; n < 4; ++n)                           \
            bfr[n] = *(const bf16x8*)&Bs[cur][wc * 64 + n * 16 + rofs][kofs];   \
        _Pragma("unroll") for (int m = 0; m < 4; ++m)                           \
            _Pragma("unroll") for (int n = 0; n < 4; ++n)                       \
                acc[m][n] = __builtin_amdgcn_mfma_f32_16x16x32_bf16(            \
                    af[m], bfr[n], acc[m][n], 0, 0, 0);                         \
        cur ^= 1;                                                               \
    }

// ---------------------------------------------------------------------------
// Kernel 3: S = mask(Qr . Kr^T), bf16 out.  grid (jt=16, it=16, lbh)
// ---------------------------------------------------------------------------
__global__ __launch_bounds__(256) void gemm1_kernel(
    const unsigned short* __restrict__ Qb, const unsigned short* __restrict__ Kb,
    unsigned short* __restrict__ S)
{
    const int jt = blockIdx.x;
    const int it = blockIdx.y;
    const int lbh = blockIdx.z;
    if (jt > it) return;   // strictly-upper tiles never read downstream

    __shared__ __align__(16) unsigned short As[2][128][32];
    __shared__ __align__(16) unsigned short Bs[2][128][32];

    const unsigned short* A  = Qb + (long)lbh * T_ * NH_ + (long)it * 128 * NH_;
    const unsigned short* Bm = Kb + (long)lbh * T_ * NH_ + (long)jt * 128 * NH_;

    GEMM_CORE(A, Bm, NH_, NH_ / 32)

    unsigned short* Sp = S + (long)lbh * T_ * T_;
    const int r0 = it * 128 + wr * 64;
    const int s0 = jt * 128 + wc * 64;
#pragma unroll
    for (int m = 0; m < 4; ++m) {
        const int rbase = r0 + m * 16 + ((lane >> 4) << 2);
#pragma unroll
        for (int i = 0; i < 4; ++i) {
            const int rr = rbase + i;
#pragma unroll
            for (int n = 0; n < 4; ++n) {
                const int ss = s0 + n * 16 + (lane & 15);
                float v = (ss < rr) ? acc[m][n][i] : 0.0f;  // strict lower mask
                Sp[(long)rr * T_ + ss] = f2bf(v);
            }
        }
    }
}

// ---------------------------------------------------------------------------
// Kernel 4: O = S . V  (B = Vt rows are d, k-contig).  grid (jn=2, it=16, lbh)
// ---------------------------------------------------------------------------
__global__ __launch_bounds__(256) void gemm2_kernel(
    const unsigned short* __restrict__ S, const unsigned short* __restrict__ Vt,
    float* __restrict__ Out, int bh0)
{
    const int jn = blockIdx.x;
    const int it = blockIdx.y;
    const int lbh = blockIdx.z;
    const int bh = bh0 + lbh;
    const int b = bh / H_;

    __shared__ __align__(16) unsigned short As[2][128][32];
    __shared__ __align__(16) unsigned short Bs[2][128][32];

    const unsigned short* A  = S + (long)lbh * T_ * T_ + (long)it * 128 * T_;
    const unsigned short* Bm = Vt + (long)b * D_ * T_ + (long)jn * 128 * T_;
    const int KT = (it + 1) * 4;   // causal: K runs to end of diagonal tile

    GEMM_CORE(A, Bm, T_, KT)

    float* Op = Out + ((long)bh * T_ + it * 128) * D_ + jn * 128;
#pragma unroll
    for (int m = 0; m < 4; ++m) {
        const int rbase = wr * 64 + m * 16 + ((lane >> 4) << 2);
#pragma unroll
        for (int i = 0; i < 4; ++i) {
            const int rr = rbase + i;
#pragma unroll
            for (int n = 0; n < 4; ++n) {
                const int cc = wc * 64 + n * 16 + (lane & 15);
                Op[(long)rr * D_ + cc] = acc[m][n][i];
            }
        }
    }
}

// ---------------------------------------------------------------------------
extern "C" void kernel_launch(void* const* d_in, const int* in_sizes, int n_in,
                              void* d_out, int out_size, void* d_ws, size_t ws_size,
                              hipStream_t stream)
{
    const float* Q = (const float*)d_in[0];
    const float* K = (const float*)d_in[1];
    const float* V = (const float*)d_in[2];
    float* Out = (float*)d_out;

    const size_t vt_elems = (size_t)B_ * D_ * T_;                 // bf16
    auto need = [&](int c) {
        return 2 * vt_elems + (size_t)c * T_ * NH_ * 2 * 2        // Qb+Kb bytes
             + (size_t)c * T_ * T_ * 2;                           // S bytes
    };
    int c;
    if      (ws_size >= need(8)) c = 8;
    else if (ws_size >= need(4)) c = 4;
    else if (ws_size >= need(2)) c = 2;
    else if (ws_size >= need(1)) c = 1;
    else return;  // workspace too small — fail loudly via validation

    unsigned short* Vt = (unsigned short*)d_ws;
    unsigned short* Qb = Vt + vt_elems;
    unsigned short* Kb = Qb + (size_t)c * T_ * NH_;
    unsigned short* Sb = Kb + (size_t)c * T_ * NH_;

    vcast_kernel<<<dim3(T_ / 64, D_ / 64, B_), 256, 0, stream>>>(V, Vt);

    for (int bh0 = 0; bh0 < B_ * H_; bh0 += c) {
        const long groups = (long)c * T_ * (NH_ / 8);
        rope_cast_kernel<<<(int)(groups / 256), 256, 0, stream>>>(Q, K, Qb, Kb, bh0);
        gemm1_kernel<<<dim3(16, 16, c), 256, 0, stream>>>(Qb, Kb, Sb);
        gemm2_kernel<<<dim3(2, 16, c), 256, 0, stream>>>(Sb, Vt, Out, bh0);
    }
}

// Round 2
// 947.097 us; speedup vs baseline: 1.1461x; 1.1461x over previous
//
#include <hip/hip_runtime.h>
#include <hip/hip_bf16.h>

#define B_ 2
#define H_ 4
#define T_ 2048
#define NH_ 8192
#define D_ 256

typedef __attribute__((ext_vector_type(4))) float f32x4;
typedef __attribute__((ext_vector_type(8))) short bf16x8;
typedef __attribute__((ext_vector_type(4))) int i32x4;

__device__ __forceinline__ unsigned short f2bf(float f) {
    union { float f; unsigned u; } v;
    v.f = f;
    unsigned u = v.u;
    unsigned r = u + 0x7FFFu + ((u >> 16) & 1u);   // RNE
    return (unsigned short)(r >> 16);
}

// ---------------------------------------------------------------------------
// Kernel 1: RoPE + cast to bf16 for Q and K
// freq[pair p] = 2^(-p/256) / (2*pi)   (theta=2^16, NH=8192 exactly)
// ---------------------------------------------------------------------------
__global__ __launch_bounds__(256) void rope_cast_kernel(
    const float* __restrict__ Q, const float* __restrict__ K,
    unsigned short* __restrict__ Qb, unsigned short* __restrict__ Kb,
    int bh0)
{
    const long gid = (long)blockIdx.x * 256 + threadIdx.x;  // one 8-elem group
    const int ng = NH_ / 8;
    const int n8 = (int)(gid % ng) * 8;
    const long row = gid / ng;              // lbh*T + t
    const int t = (int)(row % T_);
    const int lbh = (int)(row / T_);

    const long in_off  = ((long)(bh0 + lbh) * T_ + t) * NH_ + n8;
    const long out_off = ((long)lbh * T_ + t) * NH_ + n8;

    float4 qa = *(const float4*)(Q + in_off);
    float4 qb4 = *(const float4*)(Q + in_off + 4);
    float4 ka = *(const float4*)(K + in_off);
    float4 kb4 = *(const float4*)(K + in_off + 4);
    float qv[8] = {qa.x, qa.y, qa.z, qa.w, qb4.x, qb4.y, qb4.z, qb4.w};
    float kv[8] = {ka.x, ka.y, ka.z, ka.w, kb4.x, kb4.y, kb4.z, kb4.w};

    union { i32x4 v; unsigned short u[8]; } qo, ko;
    const int p0 = n8 >> 1;
    const float tf = (float)t;
#pragma unroll
    for (int j = 0; j < 4; ++j) {
        float freq = exp2f(-(float)(p0 + j) * (1.0f / 256.0f)) * 0.15915494309189535f;
        float phase = tf * freq;
        float r = phase - floorf(phase);
        float ph = r * 6.283185307179586f;
        float c = __cosf(ph);
        float s = __sinf(ph);
        float qe = qv[2 * j], qodd = qv[2 * j + 1];
        float ke = kv[2 * j], kodd = kv[2 * j + 1];
        qo.u[2 * j]     = f2bf(qe * c - qodd * s);
        qo.u[2 * j + 1] = f2bf(qodd * c + qe * s);
        ko.u[2 * j]     = f2bf(ke * c - kodd * s);
        ko.u[2 * j + 1] = f2bf(kodd * c + ke * s);
    }
    *(i32x4*)(Qb + out_off) = qo.v;
    *(i32x4*)(Kb + out_off) = ko.v;
}

// ---------------------------------------------------------------------------
// Kernel 2: V [B,T,D] fp32 -> Vt [B,D,T] bf16 (transposed cast, LDS tiled)
// ---------------------------------------------------------------------------
__global__ __launch_bounds__(256) void vcast_kernel(
    const float* __restrict__ V, unsigned short* __restrict__ Vt)
{
    __shared__ unsigned short tile[64][72];
    const int t0 = blockIdx.x * 64;
    const int d0 = blockIdx.y * 64;
    const int b = blockIdx.z;
    const int tid = threadIdx.x;
#pragma unroll
    for (int rr = 0; rr < 16; ++rr) {
        int tl = rr * 4 + (tid >> 6);
        int dl = tid & 63;
        float v = V[((long)b * T_ + (t0 + tl)) * D_ + d0 + dl];
        tile[dl][tl] = f2bf(v);
    }
    __syncthreads();
#pragma unroll
    for (int rr = 0; rr < 16; ++rr) {
        int dl = rr * 4 + (tid >> 6);
        int tl = tid & 63;
        Vt[((long)b * D_ + (d0 + dl)) * T_ + t0 + tl] = tile[dl][tl];
    }
}

// ---------------------------------------------------------------------------
// gemm1: S = mask(Qr . Kr^T), 256x256 tile, BK=32, 8 waves, triple-buffered
// LDS with counted vmcnt (T3/T4), read-swizzle both-sides (T2), setprio (T5),
// causal-flattened grid + bijective XCD swizzle (T1).
// ---------------------------------------------------------------------------
#define GLD16(g, l) __builtin_amdgcn_global_load_lds(                         \
    (const __attribute__((address_space(1))) void*)(g),                       \
    (__attribute__((address_space(3))) void*)(l), 16, 0, 0)

// stage K-tile kt into buffer SB (A:16KB + B:16KB, 4 loads/thread)
#define STAGE(SB, kt) {                                                       \
    const long ko_ = (long)(kt) * 32;                                         \
    GLD16(gA0 + ko_, &As[SB][0][0] + dst);                                    \
    GLD16(gA1 + ko_, &As[SB][128][0] + dst);                                  \
    GLD16(gB0 + ko_, &Bs[SB][0][0] + dst);                                    \
    GLD16(gB1 + ko_, &Bs[SB][128][0] + dst); }

#define BODY(t, RB, SB, LAST) {                                               \
    const bool st_ = (t) + 2 < 256;                                           \
    if (st_) STAGE(SB, (t) + 2);                                              \
    bf16x8 af[8], bv[4];                                                      \
    _Pragma("unroll") for (int m = 0; m < 8; ++m)                             \
        af[m] = *(const bf16x8*)&As[RB][wr * 128 + m * 16 + rofs][sl8];       \
    _Pragma("unroll") for (int n = 0; n < 4; ++n)                             \
        bv[n] = *(const bf16x8*)&Bs[RB][wc * 64 + n * 16 + rofs][sl8];        \
    __builtin_amdgcn_s_setprio(1);                                            \
    _Pragma("unroll") for (int m = 0; m < 8; ++m)                             \
        _Pragma("unroll") for (int n = 0; n < 4; ++n)                         \
            acc[m][n] = __builtin_amdgcn_mfma_f32_16x16x32_bf16(              \
                af[m], bv[n], acc[m][n], 0, 0, 0);                            \
    __builtin_amdgcn_s_setprio(0);                                            \
    if (!(LAST)) {                                                            \
        if (st_) asm volatile("s_waitcnt vmcnt(4)" ::: "memory");             \
        else     asm volatile("s_waitcnt vmcnt(0)" ::: "memory");             \
        __builtin_amdgcn_s_barrier();                                         \
        __builtin_amdgcn_sched_barrier(0);                                    \
    } }

__global__ __launch_bounds__(512, 2) void gemm1_kernel(
    const unsigned short* __restrict__ Qb, const unsigned short* __restrict__ Kb,
    unsigned short* __restrict__ S)
{
    __shared__ __align__(16) unsigned short As[3][256][32];
    __shared__ __align__(16) unsigned short Bs[3][256][32];

    // bijective XCD swizzle (m204 variant)
    const int nwg = gridDim.x;
    const int orig = blockIdx.x;
    const int xcd = orig & 7, q = nwg >> 3, r = nwg & 7;
    const int wg = (xcd < r ? xcd * (q + 1) : r * (q + 1) + (xcd - r) * q) + (orig >> 3);

    // triangular decode: wg -> (lbh, it, jt) with jt <= it
    const int t36 = wg % 36;
    const int lbh = wg / 36;
    int it = (int)((sqrtf(8.0f * (float)t36 + 1.0f) - 1.0f) * 0.5f);
    if ((it + 1) * (it + 2) / 2 <= t36) ++it;
    if (it * (it + 1) / 2 > t36) --it;
    const int jt = t36 - it * (it + 1) / 2;

    const int tid = threadIdx.x;
    const int lane = tid & 63;
    const int wid = tid >> 6;
    const int wr = wid >> 2;                 // 0..1 (M half)
    const int wc = wid & 3;                  // 0..3 (N quarter)
    const int rofs = lane & 15;
    // read-side swizzled 8-elem chunk: chunk = (lane>>4) ^ ((row>>1)&3); row%16==lane&15
    const int sl8 = (((lane >> 4) ^ ((lane >> 1) & 3))) << 3;

    // stage addressing: dest linear (rule 21), source pre-swizzled
    const int ss8 = (((tid & 3) ^ ((tid >> 3) & 3))) << 3;
    const int dst = tid * 8;                 // elems within [128][32] half
    const unsigned short* Ab = Qb + (long)lbh * T_ * NH_ + (long)it * 256 * NH_;
    const unsigned short* Bb = Kb + (long)lbh * T_ * NH_ + (long)jt * 256 * NH_;
    const unsigned short* gA0 = Ab + (long)(tid >> 2) * NH_ + ss8;
    const unsigned short* gA1 = gA0 + 128L * NH_;
    const unsigned short* gB0 = Bb + (long)(tid >> 2) * NH_ + ss8;
    const unsigned short* gB1 = gB0 + 128L * NH_;

    f32x4 acc[8][4];
#pragma unroll
    for (int m = 0; m < 8; ++m)
#pragma unroll
        for (int n = 0; n < 4; ++n)
            acc[m][n] = (f32x4){0.f, 0.f, 0.f, 0.f};

    // prologue: tiles 0,1 in flight; wait for tile 0 only (counted)
    STAGE(0, 0)
    STAGE(1, 1)
    asm volatile("s_waitcnt vmcnt(4)" ::: "memory");
    __builtin_amdgcn_s_barrier();
    __builtin_amdgcn_sched_barrier(0);

#pragma unroll 1
    for (int t = 0; t < 255; t += 3) {
        BODY(t,     0, 2, false)
        BODY(t + 1, 1, 0, false)
        BODY(t + 2, 2, 1, false)
    }
    BODY(255, 0, 2, true)

    // epilogue: strict-lower mask, bf16 store
    unsigned short* Sp = S + (long)lbh * T_ * T_;
    const int r0 = it * 256 + wr * 128 + ((lane >> 4) << 2);
    const int c0 = jt * 256 + wc * 64 + (lane & 15);
#pragma unroll
    for (int m = 0; m < 8; ++m) {
#pragma unroll
        for (int i = 0; i < 4; ++i) {
            const int rr = r0 + m * 16 + i;
#pragma unroll
            for (int n = 0; n < 4; ++n) {
                const int cc = c0 + n * 16;
                float v = (cc < rr) ? acc[m][n][i] : 0.0f;
                Sp[(long)rr * T_ + cc] = f2bf(v);
            }
        }
    }
}

// ---------------------------------------------------------------------------
// gemm2 support (m97 structure, 128x128): O = S . V
// ---------------------------------------------------------------------------
__device__ __forceinline__ void stage_tile(const unsigned short* g, long ldk,
                                           unsigned short* l, int tid)
{
    const int row = tid >> 2;            // 0..63
    const int col = (tid & 3) << 3;      // 0,8,16,24
    const unsigned short* g0 = g + (long)row * ldk + col;
    const unsigned short* g1 = g0 + 64 * ldk;
    unsigned short* l0 = l + tid * 8;
    unsigned short* l1 = l0 + 2048;      // rows 64..127
    GLD16(g0, l0);
    GLD16(g1, l1);
}

__global__ __launch_bounds__(256) void gemm2_kernel(
    const unsigned short* __restrict__ S, const unsigned short* __restrict__ Vt,
    float* __restrict__ Out, int bh0)
{
    const int jn = blockIdx.x;
    const int it = blockIdx.y;
    const int lbh = blockIdx.z;
    const int bh = bh0 + lbh;
    const int b = bh / H_;

    __shared__ __align__(16) unsigned short As2[2][128][32];
    __shared__ __align__(16) unsigned short Bs2[2][128][32];

    const unsigned short* A  = S + (long)lbh * T_ * T_ + (long)it * 128 * T_;
    const unsigned short* Bm = Vt + (long)b * D_ * T_ + (long)jn * 128 * T_;
    const int KT = (it + 1) * 4;   // causal: K runs to end of diagonal tile

    const int tid = threadIdx.x;
    const int lane = tid & 63;
    const int wid = tid >> 6;
    const int wr = wid >> 1;
    const int wc = wid & 1;
    f32x4 acc[4][4];
#pragma unroll
    for (int m = 0; m < 4; ++m)
#pragma unroll
        for (int n = 0; n < 4; ++n)
            acc[m][n] = (f32x4){0.f, 0.f, 0.f, 0.f};
    const int rofs = lane & 15;
    const int kofs = (lane >> 4) * 8;
    stage_tile(A, T_, &As2[0][0][0], tid);
    stage_tile(Bm, T_, &Bs2[0][0][0], tid);
    int cur = 0;
    for (int kt = 0; kt < KT; ++kt) {
        __syncthreads();
        if (kt + 1 < KT) {
            stage_tile(A + (long)(kt + 1) * 32, T_, &As2[cur ^ 1][0][0], tid);
            stage_tile(Bm + (long)(kt + 1) * 32, T_, &Bs2[cur ^ 1][0][0], tid);
        }
        bf16x8 af[4], bfr[4];
#pragma unroll
        for (int m = 0; m < 4; ++m)
            af[m] = *(const bf16x8*)&As2[cur][wr * 64 + m * 16 + rofs][kofs];
#pragma unroll
        for (int n = 0; n < 4; ++n)
            bfr[n] = *(const bf16x8*)&Bs2[cur][wc * 64 + n * 16 + rofs][kofs];
#pragma unroll
        for (int m = 0; m < 4; ++m)
#pragma unroll
            for (int n = 0; n < 4; ++n)
                acc[m][n] = __builtin_amdgcn_mfma_f32_16x16x32_bf16(
                    af[m], bfr[n], acc[m][n], 0, 0, 0);
        cur ^= 1;
    }

    float* Op = Out + ((long)bh * T_ + it * 128) * D_ + jn * 128;
#pragma unroll
    for (int m = 0; m < 4; ++m) {
        const int rbase = wr * 64 + m * 16 + ((lane >> 4) << 2);
#pragma unroll
        for (int i = 0; i < 4; ++i) {
            const int rr = rbase + i;
#pragma unroll
            for (int n = 0; n < 4; ++n) {
                const int cc = wc * 64 + n * 16 + (lane & 15);
                Op[(long)rr * D_ + cc] = acc[m][n][i];
            }
        }
    }
}

// ---------------------------------------------------------------------------
extern "C" void kernel_launch(void* const* d_in, const int* in_sizes, int n_in,
                              void* d_out, int out_size, void* d_ws, size_t ws_size,
                              hipStream_t stream)
{
    const float* Q = (const float*)d_in[0];
    const float* K = (const float*)d_in[1];
    const float* V = (const float*)d_in[2];
    float* Out = (float*)d_out;

    const size_t vt_elems = (size_t)B_ * D_ * T_;                 // bf16
    auto need = [&](int c) {
        return 2 * vt_elems + (size_t)c * T_ * NH_ * 2 * 2        // Qb+Kb bytes
             + (size_t)c * T_ * T_ * 2;                           // S bytes
    };
    int c;
    if      (ws_size >= need(8)) c = 8;
    else if (ws_size >= need(4)) c = 4;
    else if (ws_size >= need(2)) c = 2;
    else if (ws_size >= need(1)) c = 1;
    else return;

    unsigned short* Vt = (unsigned short*)d_ws;
    unsigned short* Qb = Vt + vt_elems;
    unsigned short* Kb = Qb + (size_t)c * T_ * NH_;
    unsigned short* Sb = Kb + (size_t)c * T_ * NH_;

    vcast_kernel<<<dim3(T_ / 64, D_ / 64, B_), 256, 0, stream>>>(V, Vt);

    for (int bh0 = 0; bh0 < B_ * H_; bh0 += c) {
        const long groups = (long)c * T_ * (NH_ / 8);
        rope_cast_kernel<<<(int)(groups / 256), 256, 0, stream>>>(Q, K, Qb, Kb, bh0);
        gemm1_kernel<<<dim3(c * 36), 512, 0, stream>>>(Qb, Kb, Sb);
        gemm2_kernel<<<dim3(2, 16, c), 256, 0, stream>>>(Sb, Vt, Out, bh0);
    }
}

// Round 3
// 881.865 us; speedup vs baseline: 1.2308x; 1.0740x over previous
//
#include <hip/hip_runtime.h>
#include <hip/hip_bf16.h>

#define B_ 2
#define H_ 4
#define T_ 2048
#define NH_ 8192
#define D_ 256

typedef __attribute__((ext_vector_type(4))) float f32x4;
typedef __attribute__((ext_vector_type(8))) short bf16x8;
typedef __attribute__((ext_vector_type(4))) int i32x4;

__device__ __forceinline__ unsigned short f2bf(float f) {
    union { float f; unsigned u; } v;
    v.f = f;
    unsigned u = v.u;
    unsigned r = u + 0x7FFFu + ((u >> 16) & 1u);   // RNE
    return (unsigned short)(r >> 16);
}

// ---------------------------------------------------------------------------
// Kernel 1: RoPE + cast to bf16 for Q and K
// freq[pair p] = 2^(-p/256) / (2*pi)   (theta=2^16, NH=8192 exactly)
// ---------------------------------------------------------------------------
__global__ __launch_bounds__(256) void rope_cast_kernel(
    const float* __restrict__ Q, const float* __restrict__ K,
    unsigned short* __restrict__ Qb, unsigned short* __restrict__ Kb,
    int bh0)
{
    const long gid = (long)blockIdx.x * 256 + threadIdx.x;  // one 8-elem group
    const int ng = NH_ / 8;
    const int n8 = (int)(gid % ng) * 8;
    const long row = gid / ng;              // lbh*T + t
    const int t = (int)(row % T_);
    const int lbh = (int)(row / T_);

    const long in_off  = ((long)(bh0 + lbh) * T_ + t) * NH_ + n8;
    const long out_off = ((long)lbh * T_ + t) * NH_ + n8;

    float4 qa = *(const float4*)(Q + in_off);
    float4 qb4 = *(const float4*)(Q + in_off + 4);
    float4 ka = *(const float4*)(K + in_off);
    float4 kb4 = *(const float4*)(K + in_off + 4);
    float qv[8] = {qa.x, qa.y, qa.z, qa.w, qb4.x, qb4.y, qb4.z, qb4.w};
    float kv[8] = {ka.x, ka.y, ka.z, ka.w, kb4.x, kb4.y, kb4.z, kb4.w};

    union { i32x4 v; unsigned short u[8]; } qo, ko;
    const int p0 = n8 >> 1;
    const float tf = (float)t;
#pragma unroll
    for (int j = 0; j < 4; ++j) {
        float freq = exp2f(-(float)(p0 + j) * (1.0f / 256.0f)) * 0.15915494309189535f;
        float phase = tf * freq;
        float r = phase - floorf(phase);
        float ph = r * 6.283185307179586f;
        float c = __cosf(ph);
        float s = __sinf(ph);
        float qe = qv[2 * j], qodd = qv[2 * j + 1];
        float ke = kv[2 * j], kodd = kv[2 * j + 1];
        qo.u[2 * j]     = f2bf(qe * c - qodd * s);
        qo.u[2 * j + 1] = f2bf(qodd * c + qe * s);
        ko.u[2 * j]     = f2bf(ke * c - kodd * s);
        ko.u[2 * j + 1] = f2bf(kodd * c + ke * s);
    }
    *(i32x4*)(Qb + out_off) = qo.v;
    *(i32x4*)(Kb + out_off) = ko.v;
}

// ---------------------------------------------------------------------------
// Kernel 2: V [B,T,D] fp32 -> Vt [B,D,T] bf16 (transposed cast, LDS tiled)
// ---------------------------------------------------------------------------
__global__ __launch_bounds__(256) void vcast_kernel(
    const float* __restrict__ V, unsigned short* __restrict__ Vt)
{
    __shared__ unsigned short tile[64][72];
    const int t0 = blockIdx.x * 64;
    const int d0 = blockIdx.y * 64;
    const int b = blockIdx.z;
    const int tid = threadIdx.x;
#pragma unroll
    for (int rr = 0; rr < 16; ++rr) {
        int tl = rr * 4 + (tid >> 6);
        int dl = tid & 63;
        float v = V[((long)b * T_ + (t0 + tl)) * D_ + d0 + dl];
        tile[dl][tl] = f2bf(v);
    }
    __syncthreads();
#pragma unroll
    for (int rr = 0; rr < 16; ++rr) {
        int dl = rr * 4 + (tid >> 6);
        int tl = tid & 63;
        Vt[((long)b * D_ + (d0 + dl)) * T_ + t0 + tl] = tile[dl][tl];
    }
}

// ---------------------------------------------------------------------------
// gemm1: S = mask(Qr . Kr^T), 256x256 tile, BK=32, 8 waves, triple-buffered
// LDS, counted vmcnt (T3/T4), TWO-PHASE split per K-step (m201 granularity:
// 16 MFMA per phase, dual barriers), read-swizzle both-sides (T2),
// setprio (T5), causal-flattened grid + bijective XCD swizzle (T1).
// ---------------------------------------------------------------------------
#define GLD16(g, l) __builtin_amdgcn_global_load_lds(                         \
    (const __attribute__((address_space(1))) void*)(g),                       \
    (__attribute__((address_space(3))) void*)(l), 16, 0, 0)

#define BODY2(t, RB, SB, LAST) {                                              \
    const bool st_ = (t) + 2 < 256;                                           \
    const long ko_ = (long)((t) + 2) * 32;                                    \
    bf16x8 af0[4], af1[4], bv[4];                                             \
    /* ---- phase 0: read af(rows 0-63 of wave tile) + all bv; stage A ---- */\
    _Pragma("unroll") for (int m = 0; m < 4; ++m)                             \
        af0[m] = *(const bf16x8*)&As[RB][wr * 128 + m * 16 + rofs][sl8];      \
    _Pragma("unroll") for (int n = 0; n < 4; ++n)                             \
        bv[n] = *(const bf16x8*)&Bs[RB][wc * 64 + n * 16 + rofs][sl8];        \
    if (st_) { GLD16(gA0 + ko_, &As[SB][0][0] + dst);                         \
               GLD16(gA1 + ko_, &As[SB][128][0] + dst); }                     \
    __builtin_amdgcn_s_barrier();                                             \
    __builtin_amdgcn_sched_barrier(0);                                        \
    __builtin_amdgcn_s_setprio(1);                                            \
    _Pragma("unroll") for (int m = 0; m < 4; ++m)                             \
        _Pragma("unroll") for (int n = 0; n < 4; ++n)                         \
            acc[m][n] = __builtin_amdgcn_mfma_f32_16x16x32_bf16(              \
                af0[m], bv[n], acc[m][n], 0, 0, 0);                           \
    __builtin_amdgcn_s_setprio(0);                                            \
    __builtin_amdgcn_sched_barrier(0);                                        \
    __builtin_amdgcn_s_barrier();                                             \
    /* ---- phase 1: read af(rows 64-127); stage B ---- */                    \
    _Pragma("unroll") for (int m = 0; m < 4; ++m)                             \
        af1[m] = *(const bf16x8*)&As[RB][wr * 128 + (m + 4) * 16 + rofs][sl8];\
    if (st_) { GLD16(gB0 + ko_, &Bs[SB][0][0] + dst);                         \
               GLD16(gB1 + ko_, &Bs[SB][128][0] + dst); }                     \
    __builtin_amdgcn_s_barrier();                                             \
    __builtin_amdgcn_sched_barrier(0);                                        \
    __builtin_amdgcn_s_setprio(1);                                            \
    _Pragma("unroll") for (int m = 0; m < 4; ++m)                             \
        _Pragma("unroll") for (int n = 0; n < 4; ++n)                         \
            acc[m + 4][n] = __builtin_amdgcn_mfma_f32_16x16x32_bf16(          \
                af1[m], bv[n], acc[m + 4][n], 0, 0, 0);                       \
    __builtin_amdgcn_s_setprio(0);                                            \
    __builtin_amdgcn_sched_barrier(0);                                        \
    if (!(LAST)) {                                                            \
        if (st_) asm volatile("s_waitcnt vmcnt(4)" ::: "memory");             \
        else     asm volatile("s_waitcnt vmcnt(0)" ::: "memory");             \
        __builtin_amdgcn_s_barrier();                                         \
        __builtin_amdgcn_sched_barrier(0);                                    \
    } }

__global__ __launch_bounds__(512, 2) void gemm1_kernel(
    const unsigned short* __restrict__ Qb, const unsigned short* __restrict__ Kb,
    unsigned short* __restrict__ S)
{
    __shared__ __align__(16) unsigned short As[3][256][32];
    __shared__ __align__(16) unsigned short Bs[3][256][32];

    // bijective XCD swizzle (m204 variant)
    const int nwg = gridDim.x;
    const int orig = blockIdx.x;
    const int xcd = orig & 7, q = nwg >> 3, r = nwg & 7;
    const int wg = (xcd < r ? xcd * (q + 1) : r * (q + 1) + (xcd - r) * q) + (orig >> 3);

    // triangular decode: wg -> (lbh, it, jt) with jt <= it
    const int t36 = wg % 36;
    const int lbh = wg / 36;
    int it = (int)((sqrtf(8.0f * (float)t36 + 1.0f) - 1.0f) * 0.5f);
    if ((it + 1) * (it + 2) / 2 <= t36) ++it;
    if (it * (it + 1) / 2 > t36) --it;
    const int jt = t36 - it * (it + 1) / 2;

    const int tid = threadIdx.x;
    const int lane = tid & 63;
    const int wid = tid >> 6;
    const int wr = wid >> 2;                 // 0..1 (M half)
    const int wc = wid & 3;                  // 0..3 (N quarter)
    const int rofs = lane & 15;
    // read-side swizzled 8-elem chunk (XOR involution, verified 0-conflict R1)
    const int sl8 = (((lane >> 4) ^ ((lane >> 1) & 3))) << 3;

    // stage addressing: dest linear (rule 21), source pre-swizzled
    const int ss8 = (((tid & 3) ^ ((tid >> 3) & 3))) << 3;
    const int dst = tid * 8;                 // elems within [128][32] half
    const unsigned short* Ab = Qb + (long)lbh * T_ * NH_ + (long)it * 256 * NH_;
    const unsigned short* Bb = Kb + (long)lbh * T_ * NH_ + (long)jt * 256 * NH_;
    const unsigned short* gA0 = Ab + (long)(tid >> 2) * NH_ + ss8;
    const unsigned short* gA1 = gA0 + 128L * NH_;
    const unsigned short* gB0 = Bb + (long)(tid >> 2) * NH_ + ss8;
    const unsigned short* gB1 = gB0 + 128L * NH_;

    f32x4 acc[8][4];
#pragma unroll
    for (int m = 0; m < 8; ++m)
#pragma unroll
        for (int n = 0; n < 4; ++n)
            acc[m][n] = (f32x4){0.f, 0.f, 0.f, 0.f};

    // prologue: tiles 0,1 in flight; wait for tile 0 only (counted)
    {
        GLD16(gA0, &As[0][0][0] + dst);
        GLD16(gA1, &As[0][128][0] + dst);
        GLD16(gB0, &Bs[0][0][0] + dst);
        GLD16(gB1, &Bs[0][128][0] + dst);
        GLD16(gA0 + 32, &As[1][0][0] + dst);
        GLD16(gA1 + 32, &As[1][128][0] + dst);
        GLD16(gB0 + 32, &Bs[1][0][0] + dst);
        GLD16(gB1 + 32, &Bs[1][128][0] + dst);
    }
    asm volatile("s_waitcnt vmcnt(4)" ::: "memory");
    __builtin_amdgcn_s_barrier();
    __builtin_amdgcn_sched_barrier(0);

#pragma unroll 1
    for (int t = 0; t < 255; t += 3) {
        BODY2(t,     0, 2, false)
        BODY2(t + 1, 1, 0, false)
        BODY2(t + 2, 2, 1, false)
    }
    BODY2(255, 0, 2, true)

    // epilogue: strict-lower mask, bf16 store
    unsigned short* Sp = S + (long)lbh * T_ * T_;
    const int r0 = it * 256 + wr * 128 + ((lane >> 4) << 2);
    const int c0 = jt * 256 + wc * 64 + (lane & 15);
#pragma unroll
    for (int m = 0; m < 8; ++m) {
#pragma unroll
        for (int i = 0; i < 4; ++i) {
            const int rr = r0 + m * 16 + i;
#pragma unroll
            for (int n = 0; n < 4; ++n) {
                const int cc = c0 + n * 16;
                float v = (cc < rr) ? acc[m][n][i] : 0.0f;
                Sp[(long)rr * T_ + cc] = f2bf(v);
            }
        }
    }
}

// ---------------------------------------------------------------------------
// gemm2 support (m97 structure, 128x128): O = S . V
// ---------------------------------------------------------------------------
__device__ __forceinline__ void stage_tile(const unsigned short* g, long ldk,
                                           unsigned short* l, int tid)
{
    const int row = tid >> 2;            // 0..63
    const int col = (tid & 3) << 3;      // 0,8,16,24
    const unsigned short* g0 = g + (long)row * ldk + col;
    const unsigned short* g1 = g0 + 64 * ldk;
    unsigned short* l0 = l + tid * 8;
    unsigned short* l1 = l0 + 2048;      // rows 64..127
    GLD16(g0, l0);
    GLD16(g1, l1);
}

__global__ __launch_bounds__(256) void gemm2_kernel(
    const unsigned short* __restrict__ S, const unsigned short* __restrict__ Vt,
    float* __restrict__ Out, int bh0)
{
    const int jn = blockIdx.x;
    const int it = blockIdx.y;
    const int lbh = blockIdx.z;
    const int bh = bh0 + lbh;
    const int b = bh / H_;

    __shared__ __align__(16) unsigned short As2[2][128][32];
    __shared__ __align__(16) unsigned short Bs2[2][128][32];

    const unsigned short* A  = S + (long)lbh * T_ * T_ + (long)it * 128 * T_;
    const unsigned short* Bm = Vt + (long)b * D_ * T_ + (long)jn * 128 * T_;
    const int KT = (it + 1) * 4;   // causal: K runs to end of diagonal tile

    const int tid = threadIdx.x;
    const int lane = tid & 63;
    const int wid = tid >> 6;
    const int wr = wid >> 1;
    const int wc = wid & 1;
    f32x4 acc[4][4];
#pragma unroll
    for (int m = 0; m < 4; ++m)
#pragma unroll
        for (int n = 0; n < 4; ++n)
            acc[m][n] = (f32x4){0.f, 0.f, 0.f, 0.f};
    const int rofs = lane & 15;
    const int kofs = (lane >> 4) * 8;
    stage_tile(A, T_, &As2[0][0][0], tid);
    stage_tile(Bm, T_, &Bs2[0][0][0], tid);
    int cur = 0;
    for (int kt = 0; kt < KT; ++kt) {
        __syncthreads();
        if (kt + 1 < KT) {
            stage_tile(A + (long)(kt + 1) * 32, T_, &As2[cur ^ 1][0][0], tid);
            stage_tile(Bm + (long)(kt + 1) * 32, T_, &Bs2[cur ^ 1][0][0], tid);
        }
        bf16x8 af[4], bfr[4];
#pragma unroll
        for (int m = 0; m < 4; ++m)
            af[m] = *(const bf16x8*)&As2[cur][wr * 64 + m * 16 + rofs][kofs];
#pragma unroll
        for (int n = 0; n < 4; ++n)
            bfr[n] = *(const bf16x8*)&Bs2[cur][wc * 64 + n * 16 + rofs][kofs];
#pragma unroll
        for (int m = 0; m < 4; ++m)
#pragma unroll
            for (int n = 0; n < 4; ++n)
                acc[m][n] = __builtin_amdgcn_mfma_f32_16x16x32_bf16(
                    af[m], bfr[n], acc[m][n], 0, 0, 0);
        cur ^= 1;
    }

    float* Op = Out + ((long)bh * T_ + it * 128) * D_ + jn * 128;
#pragma unroll
    for (int m = 0; m < 4; ++m) {
        const int rbase = wr * 64 + m * 16 + ((lane >> 4) << 2);
#pragma unroll
        for (int i = 0; i < 4; ++i) {
            const int rr = rbase + i;
#pragma unroll
            for (int n = 0; n < 4; ++n) {
                const int cc = wc * 64 + n * 16 + (lane & 15);
                Op[(long)rr * D_ + cc] = acc[m][n][i];
            }
        }
    }
}

// ---------------------------------------------------------------------------
extern "C" void kernel_launch(void* const* d_in, const int* in_sizes, int n_in,
                              void* d_out, int out_size, void* d_ws, size_t ws_size,
                              hipStream_t stream)
{
    const float* Q = (const float*)d_in[0];
    const float* K = (const float*)d_in[1];
    const float* V = (const float*)d_in[2];
    float* Out = (float*)d_out;

    const size_t vt_elems = (size_t)B_ * D_ * T_;                 // bf16
    auto need = [&](int c) {
        return 2 * vt_elems + (size_t)c * T_ * NH_ * 2 * 2        // Qb+Kb bytes
             + (size_t)c * T_ * T_ * 2;                           // S bytes
    };
    int c;
    if      (ws_size >= need(8)) c = 8;
    else if (ws_size >= need(4)) c = 4;
    else if (ws_size >= need(2)) c = 2;
    else if (ws_size >= need(1)) c = 1;
    else return;

    unsigned short* Vt = (unsigned short*)d_ws;
    unsigned short* Qb = Vt + vt_elems;
    unsigned short* Kb = Qb + (size_t)c * T_ * NH_;
    unsigned short* Sb = Kb + (size_t)c * T_ * NH_;

    vcast_kernel<<<dim3(T_ / 64, D_ / 64, B_), 256, 0, stream>>>(V, Vt);

    for (int bh0 = 0; bh0 < B_ * H_; bh0 += c) {
        const long groups = (long)c * T_ * (NH_ / 8);
        rope_cast_kernel<<<(int)(groups / 256), 256, 0, stream>>>(Q, K, Qb, Kb, bh0);
        gemm1_kernel<<<dim3(c * 36), 512, 0, stream>>>(Qb, Kb, Sb);
        gemm2_kernel<<<dim3(2, 16, c), 256, 0, stream>>>(Sb, Vt, Out, bh0);
    }
}

// Round 4
// 801.749 us; speedup vs baseline: 1.3538x; 1.0999x over previous
//
#include <hip/hip_runtime.h>
#include <hip/hip_bf16.h>

#define B_ 2
#define H_ 4
#define T_ 2048
#define NH_ 8192
#define D_ 256

typedef __attribute__((ext_vector_type(4))) float f32x4;
typedef __attribute__((ext_vector_type(8))) short bf16x8;
typedef __attribute__((ext_vector_type(4))) int i32x4;

__device__ __forceinline__ unsigned short f2bf(float f) {
    union { float f; unsigned u; } v;
    v.f = f;
    unsigned u = v.u;
    unsigned r = u + 0x7FFFu + ((u >> 16) & 1u);   // RNE
    return (unsigned short)(r >> 16);
}

// ---------------------------------------------------------------------------
// Kernel 1: RoPE + cast to bf16 for Q and K  (HBM-bound, ~6 TB/s: leave alone)
// freq[pair p] = 2^(-p/256) / (2*pi)   (theta=2^16, NH=8192 exactly)
// ---------------------------------------------------------------------------
__global__ __launch_bounds__(256) void rope_cast_kernel(
    const float* __restrict__ Q, const float* __restrict__ K,
    unsigned short* __restrict__ Qb, unsigned short* __restrict__ Kb,
    int bh0)
{
    const long gid = (long)blockIdx.x * 256 + threadIdx.x;  // one 8-elem group
    const int ng = NH_ / 8;
    const int n8 = (int)(gid % ng) * 8;
    const long row = gid / ng;              // lbh*T + t
    const int t = (int)(row % T_);
    const int lbh = (int)(row / T_);

    const long in_off  = ((long)(bh0 + lbh) * T_ + t) * NH_ + n8;
    const long out_off = ((long)lbh * T_ + t) * NH_ + n8;

    float4 qa = *(const float4*)(Q + in_off);
    float4 qb4 = *(const float4*)(Q + in_off + 4);
    float4 ka = *(const float4*)(K + in_off);
    float4 kb4 = *(const float4*)(K + in_off + 4);
    float qv[8] = {qa.x, qa.y, qa.z, qa.w, qb4.x, qb4.y, qb4.z, qb4.w};
    float kv[8] = {ka.x, ka.y, ka.z, ka.w, kb4.x, kb4.y, kb4.z, kb4.w};

    union { i32x4 v; unsigned short u[8]; } qo, ko;
    const int p0 = n8 >> 1;
    const float tf = (float)t;
#pragma unroll
    for (int j = 0; j < 4; ++j) {
        float freq = exp2f(-(float)(p0 + j) * (1.0f / 256.0f)) * 0.15915494309189535f;
        float phase = tf * freq;
        float r = phase - floorf(phase);
        float ph = r * 6.283185307179586f;
        float c = __cosf(ph);
        float s = __sinf(ph);
        float qe = qv[2 * j], qodd = qv[2 * j + 1];
        float ke = kv[2 * j], kodd = kv[2 * j + 1];
        qo.u[2 * j]     = f2bf(qe * c - qodd * s);
        qo.u[2 * j + 1] = f2bf(qodd * c + qe * s);
        ko.u[2 * j]     = f2bf(ke * c - kodd * s);
        ko.u[2 * j + 1] = f2bf(kodd * c + ke * s);
    }
    *(i32x4*)(Qb + out_off) = qo.v;
    *(i32x4*)(Kb + out_off) = ko.v;
}

// ---------------------------------------------------------------------------
// Kernel 2: V [B,T,D] fp32 -> Vt [B,D,T] bf16 (transposed cast, LDS tiled)
// ---------------------------------------------------------------------------
__global__ __launch_bounds__(256) void vcast_kernel(
    const float* __restrict__ V, unsigned short* __restrict__ Vt)
{
    __shared__ unsigned short tile[64][72];
    const int t0 = blockIdx.x * 64;
    const int d0 = blockIdx.y * 64;
    const int b = blockIdx.z;
    const int tid = threadIdx.x;
#pragma unroll
    for (int rr = 0; rr < 16; ++rr) {
        int tl = rr * 4 + (tid >> 6);
        int dl = tid & 63;
        float v = V[((long)b * T_ + (t0 + tl)) * D_ + d0 + dl];
        tile[dl][tl] = f2bf(v);
    }
    __syncthreads();
#pragma unroll
    for (int rr = 0; rr < 16; ++rr) {
        int dl = rr * 4 + (tid >> 6);
        int tl = tid & 63;
        Vt[((long)b * D_ + (d0 + dl)) * T_ + t0 + tl] = tile[dl][tl];
    }
}

// ---------------------------------------------------------------------------
// gemm1: S = mask(Qr . Kr^T).  BM=256 x BN=128 tile, BK=32, 4 waves (each a
// 128x64 sub-tile), triple-buffered LDS (72 KiB -> 2 blocks/CU), counted
// vmcnt(6) (T3/T4), two-phase K-step (16 MFMA/phase), both-sides XOR swizzle
// (T2, verified 0-conflict), setprio (T5), causal grid + XCD swizzle (T1).
// ---------------------------------------------------------------------------
#define GLD16(g, l) __builtin_amdgcn_global_load_lds(                         \
    (const __attribute__((address_space(1))) void*)(g),                       \
    (__attribute__((address_space(3))) void*)(l), 16, 0, 0)

#define BODY2(t, RB, SB, LAST) {                                              \
    const bool st_ = (t) + 2 < 256;                                           \
    const long ko_ = (long)((t) + 2) * 32;                                    \
    bf16x8 af0[4], af1[4], bv[4];                                             \
    /* ---- phase 0: read af rows 0-63 + all bv; stage A(t+2) 4 loads ---- */ \
    _Pragma("unroll") for (int m = 0; m < 4; ++m)                             \
        af0[m] = *(const bf16x8*)&As[RB][wr * 128 + m * 16 + rofs][sl8];      \
    _Pragma("unroll") for (int n = 0; n < 4; ++n)                             \
        bv[n] = *(const bf16x8*)&Bs[RB][wc * 64 + n * 16 + rofs][sl8];        \
    if (st_) { GLD16(gA0 + ko_, &As[SB][0][0] + dst);                         \
               GLD16(gA1 + ko_, &As[SB][64][0] + dst);                        \
               GLD16(gA2 + ko_, &As[SB][128][0] + dst);                       \
               GLD16(gA3 + ko_, &As[SB][192][0] + dst); }                     \
    __builtin_amdgcn_s_barrier();                                             \
    __builtin_amdgcn_sched_barrier(0);                                        \
    __builtin_amdgcn_s_setprio(1);                                            \
    _Pragma("unroll") for (int m = 0; m < 4; ++m)                             \
        _Pragma("unroll") for (int n = 0; n < 4; ++n)                         \
            acc[m][n] = __builtin_amdgcn_mfma_f32_16x16x32_bf16(              \
                af0[m], bv[n], acc[m][n], 0, 0, 0);                           \
    __builtin_amdgcn_s_setprio(0);                                            \
    __builtin_amdgcn_sched_barrier(0);                                        \
    __builtin_amdgcn_s_barrier();                                             \
    /* ---- phase 1: read af rows 64-127; stage B(t+2) 2 loads ---- */        \
    _Pragma("unroll") for (int m = 0; m < 4; ++m)                             \
        af1[m] = *(const bf16x8*)&As[RB][wr * 128 + (m + 4) * 16 + rofs][sl8];\
    if (st_) { GLD16(gB0 + ko_, &Bs[SB][0][0] + dst);                         \
               GLD16(gB1 + ko_, &Bs[SB][64][0] + dst); }                      \
    __builtin_amdgcn_s_barrier();                                             \
    __builtin_amdgcn_sched_barrier(0);                                        \
    __builtin_amdgcn_s_setprio(1);                                            \
    _Pragma("unroll") for (int m = 0; m < 4; ++m)                             \
        _Pragma("unroll") for (int n = 0; n < 4; ++n)                         \
            acc[m + 4][n] = __builtin_amdgcn_mfma_f32_16x16x32_bf16(          \
                af1[m], bv[n], acc[m + 4][n], 0, 0, 0);                       \
    __builtin_amdgcn_s_setprio(0);                                            \
    __builtin_amdgcn_sched_barrier(0);                                        \
    if (!(LAST)) {                                                            \
        if (st_) asm volatile("s_waitcnt vmcnt(6)" ::: "memory");             \
        else     asm volatile("s_waitcnt vmcnt(0)" ::: "memory");             \
        __builtin_amdgcn_s_barrier();                                         \
        __builtin_amdgcn_sched_barrier(0);                                    \
    } }

__global__ __launch_bounds__(256, 2) void gemm1_kernel(
    const unsigned short* __restrict__ Qb, const unsigned short* __restrict__ Kb,
    unsigned short* __restrict__ S)
{
    __shared__ __align__(16) unsigned short As[3][256][32];   // 48 KiB
    __shared__ __align__(16) unsigned short Bs[3][128][32];   // 24 KiB

    // XCD swizzle (grid = 576, divisible by 8 -> simple bijective form)
    const int nwg = gridDim.x;
    const int orig = blockIdx.x;
    const int wg = (orig & 7) * (nwg >> 3) + (orig >> 3);

    // causal tile decode: per bh, row-tiles i (256 rows), col-tiles j (128
    // cols), j <= 2i+1.  base(i) = i*i+i, count 2i+2, 72 tiles per bh.
    const int t72 = wg % 72;
    const int lbh = wg / 72;
    int it = (int)((sqrtf(4.0f * (float)t72 + 1.0f) - 1.0f) * 0.5f);
    while ((it + 1) * (it + 2) <= t72) ++it;   // (i+1)^2+(i+1) = (i+1)(i+2)
    while (it * (it + 1) > t72) --it;
    const int jt = t72 - it * (it + 1);

    const int tid = threadIdx.x;
    const int lane = tid & 63;
    const int wid = tid >> 6;
    const int wr = wid >> 1;                 // 0..1 (128-row half)
    const int wc = wid & 1;                  // 0..1 (64-col half)
    const int rofs = lane & 15;
    // read-side swizzled 8-elem chunk (XOR involution, verified 0-conflict)
    const int sl8 = (((lane >> 4) ^ ((lane >> 1) & 3))) << 3;

    // stage addressing: dest linear (rule 21), source pre-swizzled
    const int ss8 = (((tid & 3) ^ ((tid >> 3) & 3))) << 3;
    const int dst = tid * 8;                 // elems within one [64][32] quarter
    const unsigned short* Ab = Qb + (long)lbh * T_ * NH_ + (long)it * 256 * NH_;
    const unsigned short* Bb = Kb + (long)lbh * T_ * NH_ + (long)jt * 128 * NH_;
    const unsigned short* gA0 = Ab + (long)(tid >> 2) * NH_ + ss8;
    const unsigned short* gA1 = gA0 + 64L * NH_;
    const unsigned short* gA2 = gA0 + 128L * NH_;
    const unsigned short* gA3 = gA0 + 192L * NH_;
    const unsigned short* gB0 = Bb + (long)(tid >> 2) * NH_ + ss8;
    const unsigned short* gB1 = gB0 + 64L * NH_;

    f32x4 acc[8][4];
#pragma unroll
    for (int m = 0; m < 8; ++m)
#pragma unroll
        for (int n = 0; n < 4; ++n)
            acc[m][n] = (f32x4){0.f, 0.f, 0.f, 0.f};

    // prologue: tiles 0,1 in flight (12 loads); wait for tile 0 only
    {
        GLD16(gA0, &As[0][0][0] + dst);
        GLD16(gA1, &As[0][64][0] + dst);
        GLD16(gA2, &As[0][128][0] + dst);
        GLD16(gA3, &As[0][192][0] + dst);
        GLD16(gB0, &Bs[0][0][0] + dst);
        GLD16(gB1, &Bs[0][64][0] + dst);
        GLD16(gA0 + 32, &As[1][0][0] + dst);
        GLD16(gA1 + 32, &As[1][64][0] + dst);
        GLD16(gA2 + 32, &As[1][128][0] + dst);
        GLD16(gA3 + 32, &As[1][192][0] + dst);
        GLD16(gB0 + 32, &Bs[1][0][0] + dst);
        GLD16(gB1 + 32, &Bs[1][64][0] + dst);
    }
    asm volatile("s_waitcnt vmcnt(6)" ::: "memory");
    __builtin_amdgcn_s_barrier();
    __builtin_amdgcn_sched_barrier(0);

#pragma unroll 1
    for (int t = 0; t < 255; t += 3) {
        BODY2(t,     0, 2, false)
        BODY2(t + 1, 1, 0, false)
        BODY2(t + 2, 2, 1, false)
    }
    BODY2(255, 0, 2, true)

    // epilogue: strict-lower mask, bf16 store
    unsigned short* Sp = S + (long)lbh * T_ * T_;
    const int r0 = it * 256 + wr * 128 + ((lane >> 4) << 2);
    const int c0 = jt * 128 + wc * 64 + (lane & 15);
#pragma unroll
    for (int m = 0; m < 8; ++m) {
#pragma unroll
        for (int i = 0; i < 4; ++i) {
            const int rr = r0 + m * 16 + i;
#pragma unroll
            for (int n = 0; n < 4; ++n) {
                const int cc = c0 + n * 16;
                float v = (cc < rr) ? acc[m][n][i] : 0.0f;
                Sp[(long)rr * T_ + cc] = f2bf(v);
            }
        }
    }
}

// ---------------------------------------------------------------------------
// gemm2 support (m97 structure, 128x128): O = S . V
// ---------------------------------------------------------------------------
__device__ __forceinline__ void stage_tile(const unsigned short* g, long ldk,
                                           unsigned short* l, int tid)
{
    const int row = tid >> 2;            // 0..63
    const int col = (tid & 3) << 3;      // 0,8,16,24
    const unsigned short* g0 = g + (long)row * ldk + col;
    const unsigned short* g1 = g0 + 64 * ldk;
    unsigned short* l0 = l + tid * 8;
    unsigned short* l1 = l0 + 2048;      // rows 64..127
    GLD16(g0, l0);
    GLD16(g1, l1);
}

__global__ __launch_bounds__(256) void gemm2_kernel(
    const unsigned short* __restrict__ S, const unsigned short* __restrict__ Vt,
    float* __restrict__ Out, int bh0)
{
    const int jn = blockIdx.x;
    const int it = blockIdx.y;
    const int lbh = blockIdx.z;
    const int bh = bh0 + lbh;
    const int b = bh / H_;

    __shared__ __align__(16) unsigned short As2[2][128][32];
    __shared__ __align__(16) unsigned short Bs2[2][128][32];

    const unsigned short* A  = S + (long)lbh * T_ * T_ + (long)it * 128 * T_;
    const unsigned short* Bm = Vt + (long)b * D_ * T_ + (long)jn * 128 * T_;
    const int KT = (it + 1) * 4;   // causal: K runs to end of diagonal tile

    const int tid = threadIdx.x;
    const int lane = tid & 63;
    const int wid = tid >> 6;
    const int wr = wid >> 1;
    const int wc = wid & 1;
    f32x4 acc[4][4];
#pragma unroll
    for (int m = 0; m < 4; ++m)
#pragma unroll
        for (int n = 0; n < 4; ++n)
            acc[m][n] = (f32x4){0.f, 0.f, 0.f, 0.f};
    const int rofs = lane & 15;
    const int kofs = (lane >> 4) * 8;
    stage_tile(A, T_, &As2[0][0][0], tid);
    stage_tile(Bm, T_, &Bs2[0][0][0], tid);
    int cur = 0;
    for (int kt = 0; kt < KT; ++kt) {
        __syncthreads();
        if (kt + 1 < KT) {
            stage_tile(A + (long)(kt + 1) * 32, T_, &As2[cur ^ 1][0][0], tid);
            stage_tile(Bm + (long)(kt + 1) * 32, T_, &Bs2[cur ^ 1][0][0], tid);
        }
        bf16x8 af[4], bfr[4];
#pragma unroll
        for (int m = 0; m < 4; ++m)
            af[m] = *(const bf16x8*)&As2[cur][wr * 64 + m * 16 + rofs][kofs];
#pragma unroll
        for (int n = 0; n < 4; ++n)
            bfr[n] = *(const bf16x8*)&Bs2[cur][wc * 64 + n * 16 + rofs][kofs];
#pragma unroll
        for (int m = 0; m < 4; ++m)
#pragma unroll
            for (int n = 0; n < 4; ++n)
                acc[m][n] = __builtin_amdgcn_mfma_f32_16x16x32_bf16(
                    af[m], bfr[n], acc[m][n], 0, 0, 0);
        cur ^= 1;
    }

    float* Op = Out + ((long)bh * T_ + it * 128) * D_ + jn * 128;
#pragma unroll
    for (int m = 0; m < 4; ++m) {
        const int rbase = wr * 64 + m * 16 + ((lane >> 4) << 2);
#pragma unroll
        for (int i = 0; i < 4; ++i) {
            const int rr = rbase + i;
#pragma unroll
            for (int n = 0; n < 4; ++n) {
                const int cc = wc * 64 + n * 16 + (lane & 15);
                Op[(long)rr * D_ + cc] = acc[m][n][i];
            }
        }
    }
}

// ---------------------------------------------------------------------------
extern "C" void kernel_launch(void* const* d_in, const int* in_sizes, int n_in,
                              void* d_out, int out_size, void* d_ws, size_t ws_size,
                              hipStream_t stream)
{
    const float* Q = (const float*)d_in[0];
    const float* K = (const float*)d_in[1];
    const float* V = (const float*)d_in[2];
    float* Out = (float*)d_out;

    const size_t vt_elems = (size_t)B_ * D_ * T_;                 // bf16
    auto need = [&](int c) {
        return 2 * vt_elems + (size_t)c * T_ * NH_ * 2 * 2        // Qb+Kb bytes
             + (size_t)c * T_ * T_ * 2;                           // S bytes
    };
    int c;
    if      (ws_size >= need(8)) c = 8;
    else if (ws_size >= need(4)) c = 4;
    else if (ws_size >= need(2)) c = 2;
    else if (ws_size >= need(1)) c = 1;
    else return;

    unsigned short* Vt = (unsigned short*)d_ws;
    unsigned short* Qb = Vt + vt_elems;
    unsigned short* Kb = Qb + (size_t)c * T_ * NH_;
    unsigned short* Sb = Kb + (size_t)c * T_ * NH_;

    vcast_kernel<<<dim3(T_ / 64, D_ / 64, B_), 256, 0, stream>>>(V, Vt);

    for (int bh0 = 0; bh0 < B_ * H_; bh0 += c) {
        const long groups = (long)c * T_ * (NH_ / 8);
        rope_cast_kernel<<<(int)(groups / 256), 256, 0, stream>>>(Q, K, Qb, Kb, bh0);
        gemm1_kernel<<<dim3(c * 72), 256, 0, stream>>>(Qb, Kb, Sb);
        gemm2_kernel<<<dim3(2, 16, c), 256, 0, stream>>>(Sb, Vt, Out, bh0);
    }
}

// Round 5
// 792.922 us; speedup vs baseline: 1.3689x; 1.0111x over previous
//
#include <hip/hip_runtime.h>
#include <hip/hip_bf16.h>

#define B_ 2
#define H_ 4
#define T_ 2048
#define NH_ 8192
#define D_ 256

typedef __attribute__((ext_vector_type(4))) float f32x4;
typedef __attribute__((ext_vector_type(8))) short bf16x8;
typedef __attribute__((ext_vector_type(4))) int i32x4;

__device__ __forceinline__ unsigned short f2bf(float f) {
    union { float f; unsigned u; } v;
    v.f = f;
    unsigned u = v.u;
    unsigned r = u + 0x7FFFu + ((u >> 16) & 1u);   // RNE
    return (unsigned short)(r >> 16);
}

// ---------------------------------------------------------------------------
// Kernel 1: RoPE + cast to bf16 for Q and K  (HBM-bound ~250 us: near ceiling)
// freq[pair p] = 2^(-p/256) / (2*pi)   (theta=2^16, NH=8192 exactly)
// ---------------------------------------------------------------------------
__global__ __launch_bounds__(256) void rope_cast_kernel(
    const float* __restrict__ Q, const float* __restrict__ K,
    unsigned short* __restrict__ Qb, unsigned short* __restrict__ Kb,
    int bh0)
{
    const long gid = (long)blockIdx.x * 256 + threadIdx.x;  // one 8-elem group
    const int ng = NH_ / 8;
    const int n8 = (int)(gid % ng) * 8;
    const long row = gid / ng;              // lbh*T + t
    const int t = (int)(row % T_);
    const int lbh = (int)(row / T_);

    const long in_off  = ((long)(bh0 + lbh) * T_ + t) * NH_ + n8;
    const long out_off = ((long)lbh * T_ + t) * NH_ + n8;

    float4 qa = *(const float4*)(Q + in_off);
    float4 qb4 = *(const float4*)(Q + in_off + 4);
    float4 ka = *(const float4*)(K + in_off);
    float4 kb4 = *(const float4*)(K + in_off + 4);
    float qv[8] = {qa.x, qa.y, qa.z, qa.w, qb4.x, qb4.y, qb4.z, qb4.w};
    float kv[8] = {ka.x, ka.y, ka.z, ka.w, kb4.x, kb4.y, kb4.z, kb4.w};

    union { i32x4 v; unsigned short u[8]; } qo, ko;
    const int p0 = n8 >> 1;
    const float tf = (float)t;
#pragma unroll
    for (int j = 0; j < 4; ++j) {
        float freq = exp2f(-(float)(p0 + j) * (1.0f / 256.0f)) * 0.15915494309189535f;
        float phase = tf * freq;
        float r = phase - floorf(phase);
        float ph = r * 6.283185307179586f;
        float c = __cosf(ph);
        float s = __sinf(ph);
        float qe = qv[2 * j], qodd = qv[2 * j + 1];
        float ke = kv[2 * j], kodd = kv[2 * j + 1];
        qo.u[2 * j]     = f2bf(qe * c - qodd * s);
        qo.u[2 * j + 1] = f2bf(qodd * c + qe * s);
        ko.u[2 * j]     = f2bf(ke * c - kodd * s);
        ko.u[2 * j + 1] = f2bf(kodd * c + ke * s);
    }
    *(i32x4*)(Qb + out_off) = qo.v;
    *(i32x4*)(Kb + out_off) = ko.v;
}

// ---------------------------------------------------------------------------
// Kernel 2: V [B,T,D] fp32 -> Vt [B,D,T] bf16 (transposed cast, LDS tiled)
// ---------------------------------------------------------------------------
__global__ __launch_bounds__(256) void vcast_kernel(
    const float* __restrict__ V, unsigned short* __restrict__ Vt)
{
    __shared__ unsigned short tile[64][72];
    const int t0 = blockIdx.x * 64;
    const int d0 = blockIdx.y * 64;
    const int b = blockIdx.z;
    const int tid = threadIdx.x;
#pragma unroll
    for (int rr = 0; rr < 16; ++rr) {
        int tl = rr * 4 + (tid >> 6);
        int dl = tid & 63;
        float v = V[((long)b * T_ + (t0 + tl)) * D_ + d0 + dl];
        tile[dl][tl] = f2bf(v);
    }
    __syncthreads();
#pragma unroll
    for (int rr = 0; rr < 16; ++rr) {
        int dl = rr * 4 + (tid >> 6);
        int tl = tid & 63;
        Vt[((long)b * D_ + (d0 + dl)) * T_ + t0 + tl] = tile[dl][tl];
    }
}

// ---------------------------------------------------------------------------
// gemm1: S = mask(Qr . Kr^T).  BM=256 x BN=128, BK=32, 4 waves (128x64 each),
// triple-buffered LDS (72 KiB -> 2 blocks/CU), SINGLE barrier per K-step,
// counted vmcnt(6) (T3/T4), both-sides XOR swizzle (T2, 0-conflict verified),
// setprio around the 32-MFMA cluster (T5), causal grid + XCD swizzle (T1).
// Race-safety (validated R1/R4): stage targets buf[t+2]; the end-of-step
// barrier follows every wave's vmcnt(6) (its tile-t+1 loads landed) and its
// reads of buf[t] (consumed by this step's MFMAs before the barrier), so the
// next step may read buf[t+1] and overwrite buf[t-1]... (3-buffer rotation).
// ---------------------------------------------------------------------------
#define GLD16(g, l) __builtin_amdgcn_global_load_lds(                         \
    (const __attribute__((address_space(1))) void*)(g),                       \
    (__attribute__((address_space(3))) void*)(l), 16, 0, 0)

#define STEP(RB, SB, t_, DO_STAGE, VMN) {                                     \
    bf16x8 af[8], bv[4];                                                      \
    _Pragma("unroll") for (int n = 0; n < 4; ++n)                             \
        bv[n] = *(const bf16x8*)&Bs[RB][wc * 64 + n * 16 + rofs][sl8];        \
    _Pragma("unroll") for (int m = 0; m < 8; ++m)                             \
        af[m] = *(const bf16x8*)&As[RB][wr * 128 + m * 16 + rofs][sl8];       \
    if (DO_STAGE) {                                                           \
        const long ko_ = (long)((t_) + 2) * 32;                               \
        GLD16(gA0 + ko_, &As[SB][0][0] + dst);                                \
        GLD16(gA1 + ko_, &As[SB][64][0] + dst);                               \
        GLD16(gA2 + ko_, &As[SB][128][0] + dst);                              \
        GLD16(gA3 + ko_, &As[SB][192][0] + dst);                              \
        GLD16(gB0 + ko_, &Bs[SB][0][0] + dst);                                \
        GLD16(gB1 + ko_, &Bs[SB][64][0] + dst);                               \
    }                                                                         \
    __builtin_amdgcn_s_setprio(1);                                            \
    _Pragma("unroll") for (int m = 0; m < 8; ++m)                             \
        _Pragma("unroll") for (int n = 0; n < 4; ++n)                         \
            acc[m][n] = __builtin_amdgcn_mfma_f32_16x16x32_bf16(              \
                af[m], bv[n], acc[m][n], 0, 0, 0);                            \
    __builtin_amdgcn_s_setprio(0);                                            \
    if ((VMN) == 6)      asm volatile("s_waitcnt vmcnt(6)" ::: "memory");     \
    else if ((VMN) == 0) asm volatile("s_waitcnt vmcnt(0)" ::: "memory");     \
    if ((VMN) >= 0) { __builtin_amdgcn_s_barrier();                           \
                      __builtin_amdgcn_sched_barrier(0); }                    \
}

__global__ __launch_bounds__(256, 2) void gemm1_kernel(
    const unsigned short* __restrict__ Qb, const unsigned short* __restrict__ Kb,
    unsigned short* __restrict__ S)
{
    __shared__ __align__(16) unsigned short As[3][256][32];   // 48 KiB
    __shared__ __align__(16) unsigned short Bs[3][128][32];   // 24 KiB

    // XCD swizzle (grid = 576, divisible by 8 -> simple bijective form)
    const int nwg = gridDim.x;
    const int orig = blockIdx.x;
    const int wg = (orig & 7) * (nwg >> 3) + (orig >> 3);

    // causal tile decode: per bh, row-tiles i (256 rows), col-tiles j (128
    // cols), j <= 2i+1.  base(i) = i*i+i, count 2i+2, 72 tiles per bh.
    const int t72 = wg % 72;
    const int lbh = wg / 72;
    int it = (int)((sqrtf(4.0f * (float)t72 + 1.0f) - 1.0f) * 0.5f);
    while ((it + 1) * (it + 2) <= t72) ++it;
    while (it * (it + 1) > t72) --it;
    const int jt = t72 - it * (it + 1);

    const int tid = threadIdx.x;
    const int lane = tid & 63;
    const int wid = tid >> 6;
    const int wr = wid >> 1;                 // 0..1 (128-row half)
    const int wc = wid & 1;                  // 0..1 (64-col half)
    const int rofs = lane & 15;
    // read-side swizzled 8-elem chunk (XOR involution, verified 0-conflict)
    const int sl8 = (((lane >> 4) ^ ((lane >> 1) & 3))) << 3;

    // stage addressing: dest linear (rule 21), source pre-swizzled
    const int ss8 = (((tid & 3) ^ ((tid >> 3) & 3))) << 3;
    const int dst = tid * 8;                 // elems within one [64][32] quarter
    const unsigned short* Ab = Qb + (long)lbh * T_ * NH_ + (long)it * 256 * NH_;
    const unsigned short* Bb = Kb + (long)lbh * T_ * NH_ + (long)jt * 128 * NH_;
    const unsigned short* gA0 = Ab + (long)(tid >> 2) * NH_ + ss8;
    const unsigned short* gA1 = gA0 + 64L * NH_;
    const unsigned short* gA2 = gA0 + 128L * NH_;
    const unsigned short* gA3 = gA0 + 192L * NH_;
    const unsigned short* gB0 = Bb + (long)(tid >> 2) * NH_ + ss8;
    const unsigned short* gB1 = gB0 + 64L * NH_;

    f32x4 acc[8][4];
#pragma unroll
    for (int m = 0; m < 8; ++m)
#pragma unroll
        for (int n = 0; n < 4; ++n)
            acc[m][n] = (f32x4){0.f, 0.f, 0.f, 0.f};

    // prologue: tiles 0,1 in flight (12 loads); wait for tile 0 only
    {
        GLD16(gA0, &As[0][0][0] + dst);
        GLD16(gA1, &As[0][64][0] + dst);
        GLD16(gA2, &As[0][128][0] + dst);
        GLD16(gA3, &As[0][192][0] + dst);
        GLD16(gB0, &Bs[0][0][0] + dst);
        GLD16(gB1, &Bs[0][64][0] + dst);
        GLD16(gA0 + 32, &As[1][0][0] + dst);
        GLD16(gA1 + 32, &As[1][64][0] + dst);
        GLD16(gA2 + 32, &As[1][128][0] + dst);
        GLD16(gA3 + 32, &As[1][192][0] + dst);
        GLD16(gB0 + 32, &Bs[1][0][0] + dst);
        GLD16(gB1 + 32, &Bs[1][64][0] + dst);
    }
    asm volatile("s_waitcnt vmcnt(6)" ::: "memory");
    __builtin_amdgcn_s_barrier();
    __builtin_amdgcn_sched_barrier(0);

#pragma unroll 1
    for (int t = 0; t < 252; t += 3) {
        STEP(0, 2, t,     true, 6)
        STEP(1, 0, t + 1, true, 6)
        STEP(2, 1, t + 2, true, 6)
    }
    STEP(0, 2, 252, true, 6)
    STEP(1, 0, 253, true, 6)
    STEP(2, 1, 254, false, 0)
    STEP(0, 0, 255, false, -1)

    // epilogue: strict-lower mask, bf16 store
    unsigned short* Sp = S + (long)lbh * T_ * T_;
    const int r0 = it * 256 + wr * 128 + ((lane >> 4) << 2);
    const int c0 = jt * 128 + wc * 64 + (lane & 15);
#pragma unroll
    for (int m = 0; m < 8; ++m) {
#pragma unroll
        for (int i = 0; i < 4; ++i) {
            const int rr = r0 + m * 16 + i;
#pragma unroll
            for (int n = 0; n < 4; ++n) {
                const int cc = c0 + n * 16;
                float v = (cc < rr) ? acc[m][n][i] : 0.0f;
                Sp[(long)rr * T_ + cc] = f2bf(v);
            }
        }
    }
}

// ---------------------------------------------------------------------------
// gemm2 support (m97 structure, 128x128): O = S . V
// ---------------------------------------------------------------------------
__device__ __forceinline__ void stage_tile(const unsigned short* g, long ldk,
                                           unsigned short* l, int tid)
{
    const int row = tid >> 2;            // 0..63
    const int col = (tid & 3) << 3;      // 0,8,16,24
    const unsigned short* g0 = g + (long)row * ldk + col;
    const unsigned short* g1 = g0 + 64 * ldk;
    unsigned short* l0 = l + tid * 8;
    unsigned short* l1 = l0 + 2048;      // rows 64..127
    GLD16(g0, l0);
    GLD16(g1, l1);
}

__global__ __launch_bounds__(256) void gemm2_kernel(
    const unsigned short* __restrict__ S, const unsigned short* __restrict__ Vt,
    float* __restrict__ Out, int bh0)
{
    const int jn = blockIdx.x;
    const int it = blockIdx.y;
    const int lbh = blockIdx.z;
    const int bh = bh0 + lbh;
    const int b = bh / H_;

    __shared__ __align__(16) unsigned short As2[2][128][32];
    __shared__ __align__(16) unsigned short Bs2[2][128][32];

    const unsigned short* A  = S + (long)lbh * T_ * T_ + (long)it * 128 * T_;
    const unsigned short* Bm = Vt + (long)b * D_ * T_ + (long)jn * 128 * T_;
    const int KT = (it + 1) * 4;   // causal: K runs to end of diagonal tile

    const int tid = threadIdx.x;
    const int lane = tid & 63;
    const int wid = tid >> 6;
    const int wr = wid >> 1;
    const int wc = wid & 1;
    f32x4 acc[4][4];
#pragma unroll
    for (int m = 0; m < 4; ++m)
#pragma unroll
        for (int n = 0; n < 4; ++n)
            acc[m][n] = (f32x4){0.f, 0.f, 0.f, 0.f};
    const int rofs = lane & 15;
    const int kofs = (lane >> 4) * 8;
    stage_tile(A, T_, &As2[0][0][0], tid);
    stage_tile(Bm, T_, &Bs2[0][0][0], tid);
    int cur = 0;
    for (int kt = 0; kt < KT; ++kt) {
        __syncthreads();
        if (kt + 1 < KT) {
            stage_tile(A + (long)(kt + 1) * 32, T_, &As2[cur ^ 1][0][0], tid);
            stage_tile(Bm + (long)(kt + 1) * 32, T_, &Bs2[cur ^ 1][0][0], tid);
        }
        bf16x8 af[4], bfr[4];
#pragma unroll
        for (int m = 0; m < 4; ++m)
            af[m] = *(const bf16x8*)&As2[cur][wr * 64 + m * 16 + rofs][kofs];
#pragma unroll
        for (int n = 0; n < 4; ++n)
            bfr[n] = *(const bf16x8*)&Bs2[cur][wc * 64 + n * 16 + rofs][kofs];
#pragma unroll
        for (int m = 0; m < 4; ++m)
#pragma unroll
            for (int n = 0; n < 4; ++n)
                acc[m][n] = __builtin_amdgcn_mfma_f32_16x16x32_bf16(
                    af[m], bfr[n], acc[m][n], 0, 0, 0);
        cur ^= 1;
    }

    float* Op = Out + ((long)bh * T_ + it * 128) * D_ + jn * 128;
#pragma unroll
    for (int m = 0; m < 4; ++m) {
        const int rbase = wr * 64 + m * 16 + ((lane >> 4) << 2);
#pragma unroll
        for (int i = 0; i < 4; ++i) {
            const int rr = rbase + i;
#pragma unroll
            for (int n = 0; n < 4; ++n) {
                const int cc = wc * 64 + n * 16 + (lane & 15);
                Op[(long)rr * D_ + cc] = acc[m][n][i];
            }
        }
    }
}

// ---------------------------------------------------------------------------
extern "C" void kernel_launch(void* const* d_in, const int* in_sizes, int n_in,
                              void* d_out, int out_size, void* d_ws, size_t ws_size,
                              hipStream_t stream)
{
    const float* Q = (const float*)d_in[0];
    const float* K = (const float*)d_in[1];
    const float* V = (const float*)d_in[2];
    float* Out = (float*)d_out;

    const size_t vt_elems = (size_t)B_ * D_ * T_;                 // bf16
    auto need = [&](int c) {
        return 2 * vt_elems + (size_t)c * T_ * NH_ * 2 * 2        // Qb+Kb bytes
             + (size_t)c * T_ * T_ * 2;                           // S bytes
    };
    int c;
    if      (ws_size >= need(8)) c = 8;
    else if (ws_size >= need(4)) c = 4;
    else if (ws_size >= need(2)) c = 2;
    else if (ws_size >= need(1)) c = 1;
    else return;

    unsigned short* Vt = (unsigned short*)d_ws;
    unsigned short* Qb = Vt + vt_elems;
    unsigned short* Kb = Qb + (size_t)c * T_ * NH_;
    unsigned short* Sb = Kb + (size_t)c * T_ * NH_;

    vcast_kernel<<<dim3(T_ / 64, D_ / 64, B_), 256, 0, stream>>>(V, Vt);

    for (int bh0 = 0; bh0 < B_ * H_; bh0 += c) {
        const long groups = (long)c * T_ * (NH_ / 8);
        rope_cast_kernel<<<(int)(groups / 256), 256, 0, stream>>>(Q, K, Qb, Kb, bh0);
        gemm1_kernel<<<dim3(c * 72), 256, 0, stream>>>(Qb, Kb, Sb);
        gemm2_kernel<<<dim3(2, 16, c), 256, 0, stream>>>(Sb, Vt, Out, bh0);
    }
}

// Round 6
// 776.026 us; speedup vs baseline: 1.3987x; 1.0218x over previous
//
#include <hip/hip_runtime.h>
#include <hip/hip_bf16.h>

#define B_ 2
#define H_ 4
#define T_ 2048
#define NH_ 8192
#define D_ 256

typedef __attribute__((ext_vector_type(4))) float f32x4;
typedef __attribute__((ext_vector_type(8))) short bf16x8;
typedef __attribute__((ext_vector_type(4))) int i32x4;

__device__ __forceinline__ unsigned short f2bf(float f) {
    union { float f; unsigned u; } v;
    v.f = f;
    unsigned u = v.u;
    unsigned r = u + 0x7FFFu + ((u >> 16) & 1u);   // RNE
    return (unsigned short)(r >> 16);
}

// ---------------------------------------------------------------------------
// Kernel 1: RoPE + cast to bf16 for Q and K  (HBM-bound ~240 us: at ceiling)
// freq[pair p] = 2^(-p/256) / (2*pi)   (theta=2^16, NH=8192 exactly)
// ---------------------------------------------------------------------------
__global__ __launch_bounds__(256) void rope_cast_kernel(
    const float* __restrict__ Q, const float* __restrict__ K,
    unsigned short* __restrict__ Qb, unsigned short* __restrict__ Kb,
    int bh0)
{
    const long gid = (long)blockIdx.x * 256 + threadIdx.x;  // one 8-elem group
    const int ng = NH_ / 8;
    const int n8 = (int)(gid % ng) * 8;
    const long row = gid / ng;              // lbh*T + t
    const int t = (int)(row % T_);
    const int lbh = (int)(row / T_);

    const long in_off  = ((long)(bh0 + lbh) * T_ + t) * NH_ + n8;
    const long out_off = ((long)lbh * T_ + t) * NH_ + n8;

    float4 qa = *(const float4*)(Q + in_off);
    float4 qb4 = *(const float4*)(Q + in_off + 4);
    float4 ka = *(const float4*)(K + in_off);
    float4 kb4 = *(const float4*)(K + in_off + 4);
    float qv[8] = {qa.x, qa.y, qa.z, qa.w, qb4.x, qb4.y, qb4.z, qb4.w};
    float kv[8] = {ka.x, ka.y, ka.z, ka.w, kb4.x, kb4.y, kb4.z, kb4.w};

    union { i32x4 v; unsigned short u[8]; } qo, ko;
    const int p0 = n8 >> 1;
    const float tf = (float)t;
#pragma unroll
    for (int j = 0; j < 4; ++j) {
        float freq = exp2f(-(float)(p0 + j) * (1.0f / 256.0f)) * 0.15915494309189535f;
        float phase = tf * freq;
        float r = phase - floorf(phase);
        float ph = r * 6.283185307179586f;
        float c = __cosf(ph);
        float s = __sinf(ph);
        float qe = qv[2 * j], qodd = qv[2 * j + 1];
        float ke = kv[2 * j], kodd = kv[2 * j + 1];
        qo.u[2 * j]     = f2bf(qe * c - qodd * s);
        qo.u[2 * j + 1] = f2bf(qodd * c + qe * s);
        ko.u[2 * j]     = f2bf(ke * c - kodd * s);
        ko.u[2 * j + 1] = f2bf(kodd * c + ke * s);
    }
    *(i32x4*)(Qb + out_off) = qo.v;
    *(i32x4*)(Kb + out_off) = ko.v;
}

// ---------------------------------------------------------------------------
// Kernel 2: V [B,T,D] fp32 -> Vt [B,D,T] bf16 (transposed cast, LDS tiled)
// ---------------------------------------------------------------------------
__global__ __launch_bounds__(256) void vcast_kernel(
    const float* __restrict__ V, unsigned short* __restrict__ Vt)
{
    __shared__ unsigned short tile[64][72];
    const int t0 = blockIdx.x * 64;
    const int d0 = blockIdx.y * 64;
    const int b = blockIdx.z;
    const int tid = threadIdx.x;
#pragma unroll
    for (int rr = 0; rr < 16; ++rr) {
        int tl = rr * 4 + (tid >> 6);
        int dl = tid & 63;
        float v = V[((long)b * T_ + (t0 + tl)) * D_ + d0 + dl];
        tile[dl][tl] = f2bf(v);
    }
    __syncthreads();
#pragma unroll
    for (int rr = 0; rr < 16; ++rr) {
        int dl = rr * 4 + (tid >> 6);
        int tl = tid & 63;
        Vt[((long)b * D_ + (d0 + dl)) * T_ + t0 + tl] = tile[dl][tl];
    }
}

// ---------------------------------------------------------------------------
// gemm1: S = mask(Qr . Kr^T).  BM=256 x BN=128, BK=32, 4 waves (128x64 each),
// triple-buffered LDS (72 KiB -> 2 blocks/CU), counted vmcnt(6),
// REGISTER-PIPELINED step: enter each K-step with G1 operands (af03,bv)
// already in regs (pre-read post-barrier of previous step); read af47 under
// the G1 MFMA cluster; pre-read next tile's af03/bv after this step's
// barrier.  Breaks the read-burst/MFMA-burst convoy of the lockstep design.
// Race-safety: pre-reads of buf[t+1] occur after the barrier that follows
// ALL waves' vmcnt(6) proving buf[t+1]'s stage landed; buf[t+1] is next
// overwritten at step t+2 (one more barrier later).  3-buffer rotation as
// validated in R1-R5.
// ---------------------------------------------------------------------------
#define GLD16(g, l) __builtin_amdgcn_global_load_lds(                         \
    (const __attribute__((address_space(1))) void*)(g),                       \
    (__attribute__((address_space(3))) void*)(l), 16, 0, 0)

#define PSTEP(CAF03, CAF47, CBV, NAF03, NBV, RB, NB, SB, t_, DO_STAGE, MODE) {  \
    _Pragma("unroll") for (int m = 0; m < 4; ++m)                               \
        CAF47[m] = *(const bf16x8*)&As[RB][wr * 128 + (m + 4) * 16 + rofs][sl8];\
    if (DO_STAGE) {                                                             \
        const long ko_ = (long)((t_) + 2) * 32;                                 \
        GLD16(gA0 + ko_, &As[SB][0][0] + dst);                                  \
        GLD16(gA1 + ko_, &As[SB][64][0] + dst);                                 \
        GLD16(gA2 + ko_, &As[SB][128][0] + dst);                                \
        GLD16(gA3 + ko_, &As[SB][192][0] + dst);                                \
        GLD16(gB0 + ko_, &Bs[SB][0][0] + dst);                                  \
        GLD16(gB1 + ko_, &Bs[SB][64][0] + dst);                                 \
    }                                                                           \
    __builtin_amdgcn_s_setprio(1);                                              \
    _Pragma("unroll") for (int m = 0; m < 4; ++m)                               \
        _Pragma("unroll") for (int n = 0; n < 4; ++n)                           \
            acc[m][n] = __builtin_amdgcn_mfma_f32_16x16x32_bf16(                \
                CAF03[m], CBV[n], acc[m][n], 0, 0, 0);                          \
    _Pragma("unroll") for (int m = 0; m < 4; ++m)                               \
        _Pragma("unroll") for (int n = 0; n < 4; ++n)                           \
            acc[m + 4][n] = __builtin_amdgcn_mfma_f32_16x16x32_bf16(            \
                CAF47[m], CBV[n], acc[m + 4][n], 0, 0, 0);                      \
    __builtin_amdgcn_s_setprio(0);                                              \
    if ((MODE) >= 0) {                                                          \
        if ((MODE) == 6) asm volatile("s_waitcnt vmcnt(6)" ::: "memory");       \
        else             asm volatile("s_waitcnt vmcnt(0)" ::: "memory");       \
        __builtin_amdgcn_s_barrier();                                           \
        __builtin_amdgcn_sched_barrier(0);                                      \
        _Pragma("unroll") for (int m = 0; m < 4; ++m)                           \
            NAF03[m] = *(const bf16x8*)&As[NB][wr * 128 + m * 16 + rofs][sl8];  \
        _Pragma("unroll") for (int n = 0; n < 4; ++n)                           \
            NBV[n] = *(const bf16x8*)&Bs[NB][wc * 64 + n * 16 + rofs][sl8];     \
    }                                                                           \
}

__global__ __launch_bounds__(256, 2) void gemm1_kernel(
    const unsigned short* __restrict__ Qb, const unsigned short* __restrict__ Kb,
    unsigned short* __restrict__ S)
{
    __shared__ __align__(16) unsigned short As[3][256][32];   // 48 KiB
    __shared__ __align__(16) unsigned short Bs[3][128][32];   // 24 KiB

    // XCD swizzle (grid = 576, divisible by 8 -> simple bijective form)
    const int nwg = gridDim.x;
    const int orig = blockIdx.x;
    const int wg = (orig & 7) * (nwg >> 3) + (orig >> 3);

    // causal tile decode: per bh, row-tiles i (256 rows), col-tiles j (128
    // cols), j <= 2i+1.  base(i) = i*i+i, count 2i+2, 72 tiles per bh.
    const int t72 = wg % 72;
    const int lbh = wg / 72;
    int it = (int)((sqrtf(4.0f * (float)t72 + 1.0f) - 1.0f) * 0.5f);
    while ((it + 1) * (it + 2) <= t72) ++it;
    while (it * (it + 1) > t72) --it;
    const int jt = t72 - it * (it + 1);

    const int tid = threadIdx.x;
    const int lane = tid & 63;
    const int wid = tid >> 6;
    const int wr = wid >> 1;                 // 0..1 (128-row half)
    const int wc = wid & 1;                  // 0..1 (64-col half)
    const int rofs = lane & 15;
    // read-side swizzled 8-elem chunk (XOR involution, verified 0-conflict)
    const int sl8 = (((lane >> 4) ^ ((lane >> 1) & 3))) << 3;

    // stage addressing: dest linear (rule 21), source pre-swizzled
    const int ss8 = (((tid & 3) ^ ((tid >> 3) & 3))) << 3;
    const int dst = tid * 8;                 // elems within one [64][32] quarter
    const unsigned short* Ab = Qb + (long)lbh * T_ * NH_ + (long)it * 256 * NH_;
    const unsigned short* Bb = Kb + (long)lbh * T_ * NH_ + (long)jt * 128 * NH_;
    const unsigned short* gA0 = Ab + (long)(tid >> 2) * NH_ + ss8;
    const unsigned short* gA1 = gA0 + 64L * NH_;
    const unsigned short* gA2 = gA0 + 128L * NH_;
    const unsigned short* gA3 = gA0 + 192L * NH_;
    const unsigned short* gB0 = Bb + (long)(tid >> 2) * NH_ + ss8;
    const unsigned short* gB1 = gB0 + 64L * NH_;

    f32x4 acc[8][4];
#pragma unroll
    for (int m = 0; m < 8; ++m)
#pragma unroll
        for (int n = 0; n < 4; ++n)
            acc[m][n] = (f32x4){0.f, 0.f, 0.f, 0.f};

    // prologue: tiles 0,1 in flight (12 loads); wait for tile 0 only
    {
        GLD16(gA0, &As[0][0][0] + dst);
        GLD16(gA1, &As[0][64][0] + dst);
        GLD16(gA2, &As[0][128][0] + dst);
        GLD16(gA3, &As[0][192][0] + dst);
        GLD16(gB0, &Bs[0][0][0] + dst);
        GLD16(gB1, &Bs[0][64][0] + dst);
        GLD16(gA0 + 32, &As[1][0][0] + dst);
        GLD16(gA1 + 32, &As[1][64][0] + dst);
        GLD16(gA2 + 32, &As[1][128][0] + dst);
        GLD16(gA3 + 32, &As[1][192][0] + dst);
        GLD16(gB0 + 32, &Bs[1][0][0] + dst);
        GLD16(gB1 + 32, &Bs[1][64][0] + dst);
    }
    asm volatile("s_waitcnt vmcnt(6)" ::: "memory");
    __builtin_amdgcn_s_barrier();
    __builtin_amdgcn_sched_barrier(0);

    bf16x8 af03x[4], af47x[4], bvx[4];
    bf16x8 af03y[4], af47y[4], bvy[4];
#pragma unroll
    for (int m = 0; m < 4; ++m)
        af03x[m] = *(const bf16x8*)&As[0][wr * 128 + m * 16 + rofs][sl8];
#pragma unroll
    for (int n = 0; n < 4; ++n)
        bvx[n] = *(const bf16x8*)&Bs[0][wc * 64 + n * 16 + rofs][sl8];

#pragma unroll 1
    for (int t = 0; t < 252; t += 6) {
        PSTEP(af03x, af47x, bvx, af03y, bvy, 0, 1, 2, t,     true, 6)
        PSTEP(af03y, af47y, bvy, af03x, bvx, 1, 2, 0, t + 1, true, 6)
        PSTEP(af03x, af47x, bvx, af03y, bvy, 2, 0, 1, t + 2, true, 6)
        PSTEP(af03y, af47y, bvy, af03x, bvx, 0, 1, 2, t + 3, true, 6)
        PSTEP(af03x, af47x, bvx, af03y, bvy, 1, 2, 0, t + 4, true, 6)
        PSTEP(af03y, af47y, bvy, af03x, bvx, 2, 0, 1, t + 5, true, 6)
    }
    PSTEP(af03x, af47x, bvx, af03y, bvy, 0, 1, 2, 252, true, 6)
    PSTEP(af03y, af47y, bvy, af03x, bvx, 1, 2, 0, 253, true, 6)
    PSTEP(af03x, af47x, bvx, af03y, bvy, 2, 0, 1, 254, false, 0)
    PSTEP(af03y, af47y, bvy, af03x, bvx, 0, 1, 2, 255, false, -1)

    // epilogue: strict-lower mask, bf16 store
    unsigned short* Sp = S + (long)lbh * T_ * T_;
    const int r0 = it * 256 + wr * 128 + ((lane >> 4) << 2);
    const int c0 = jt * 128 + wc * 64 + (lane & 15);
#pragma unroll
    for (int m = 0; m < 8; ++m) {
#pragma unroll
        for (int i = 0; i < 4; ++i) {
            const int rr = r0 + m * 16 + i;
#pragma unroll
            for (int n = 0; n < 4; ++n) {
                const int cc = c0 + n * 16;
                float v = (cc < rr) ? acc[m][n][i] : 0.0f;
                Sp[(long)rr * T_ + cc] = f2bf(v);
            }
        }
    }
}

// ---------------------------------------------------------------------------
// gemm2 support (m97 structure, 128x128): O = S . V
// ---------------------------------------------------------------------------
__device__ __forceinline__ void stage_tile(const unsigned short* g, long ldk,
                                           unsigned short* l, int tid)
{
    const int row = tid >> 2;            // 0..63
    const int col = (tid & 3) << 3;      // 0,8,16,24
    const unsigned short* g0 = g + (long)row * ldk + col;
    const unsigned short* g1 = g0 + 64 * ldk;
    unsigned short* l0 = l + tid * 8;
    unsigned short* l1 = l0 + 2048;      // rows 64..127
    GLD16(g0, l0);
    GLD16(g1, l1);
}

__global__ __launch_bounds__(256) void gemm2_kernel(
    const unsigned short* __restrict__ S, const unsigned short* __restrict__ Vt,
    float* __restrict__ Out, int bh0)
{
    const int jn = blockIdx.x;
    const int it = blockIdx.y;
    const int lbh = blockIdx.z;
    const int bh = bh0 + lbh;
    const int b = bh / H_;

    __shared__ __align__(16) unsigned short As2[2][128][32];
    __shared__ __align__(16) unsigned short Bs2[2][128][32];

    const unsigned short* A  = S + (long)lbh * T_ * T_ + (long)it * 128 * T_;
    const unsigned short* Bm = Vt + (long)b * D_ * T_ + (long)jn * 128 * T_;
    const int KT = (it + 1) * 4;   // causal: K runs to end of diagonal tile

    const int tid = threadIdx.x;
    const int lane = tid & 63;
    const int wid = tid >> 6;
    const int wr = wid >> 1;
    const int wc = wid & 1;
    f32x4 acc[4][4];
#pragma unroll
    for (int m = 0; m < 4; ++m)
#pragma unroll
        for (int n = 0; n < 4; ++n)
            acc[m][n] = (f32x4){0.f, 0.f, 0.f, 0.f};
    const int rofs = lane & 15;
    const int kofs = (lane >> 4) * 8;
    stage_tile(A, T_, &As2[0][0][0], tid);
    stage_tile(Bm, T_, &Bs2[0][0][0], tid);
    int cur = 0;
    for (int kt = 0; kt < KT; ++kt) {
        __syncthreads();
        if (kt + 1 < KT) {
            stage_tile(A + (long)(kt + 1) * 32, T_, &As2[cur ^ 1][0][0], tid);
            stage_tile(Bm + (long)(kt + 1) * 32, T_, &Bs2[cur ^ 1][0][0], tid);
        }
        bf16x8 af[4], bfr[4];
#pragma unroll
        for (int m = 0; m < 4; ++m)
            af[m] = *(const bf16x8*)&As2[cur][wr * 64 + m * 16 + rofs][kofs];
#pragma unroll
        for (int n = 0; n < 4; ++n)
            bfr[n] = *(const bf16x8*)&Bs2[cur][wc * 64 + n * 16 + rofs][kofs];
#pragma unroll
        for (int m = 0; m < 4; ++m)
#pragma unroll
            for (int n = 0; n < 4; ++n)
                acc[m][n] = __builtin_amdgcn_mfma_f32_16x16x32_bf16(
                    af[m], bfr[n], acc[m][n], 0, 0, 0);
        cur ^= 1;
    }

    float* Op = Out + ((long)bh * T_ + it * 128) * D_ + jn * 128;
#pragma unroll
    for (int m = 0; m < 4; ++m) {
        const int rbase = wr * 64 + m * 16 + ((lane >> 4) << 2);
#pragma unroll
        for (int i = 0; i < 4; ++i) {
            const int rr = rbase + i;
#pragma unroll
            for (int n = 0; n < 4; ++n) {
                const int cc = wc * 64 + n * 16 + (lane & 15);
                Op[(long)rr * D_ + cc] = acc[m][n][i];
            }
        }
    }
}

// ---------------------------------------------------------------------------
extern "C" void kernel_launch(void* const* d_in, const int* in_sizes, int n_in,
                              void* d_out, int out_size, void* d_ws, size_t ws_size,
                              hipStream_t stream)
{
    const float* Q = (const float*)d_in[0];
    const float* K = (const float*)d_in[1];
    const float* V = (const float*)d_in[2];
    float* Out = (float*)d_out;

    const size_t vt_elems = (size_t)B_ * D_ * T_;                 // bf16
    auto need = [&](int c) {
        return 2 * vt_elems + (size_t)c * T_ * NH_ * 2 * 2        // Qb+Kb bytes
             + (size_t)c * T_ * T_ * 2;                           // S bytes
    };
    int c;
    if      (ws_size >= need(8)) c = 8;
    else if (ws_size >= need(4)) c = 4;
    else if (ws_size >= need(2)) c = 2;
    else if (ws_size >= need(1)) c = 1;
    else return;

    unsigned short* Vt = (unsigned short*)d_ws;
    unsigned short* Qb = Vt + vt_elems;
    unsigned short* Kb = Qb + (size_t)c * T_ * NH_;
    unsigned short* Sb = Kb + (size_t)c * T_ * NH_;

    vcast_kernel<<<dim3(T_ / 64, D_ / 64, B_), 256, 0, stream>>>(V, Vt);

    for (int bh0 = 0; bh0 < B_ * H_; bh0 += c) {
        const long groups = (long)c * T_ * (NH_ / 8);
        rope_cast_kernel<<<(int)(groups / 256), 256, 0, stream>>>(Q, K, Qb, Kb, bh0);
        gemm1_kernel<<<dim3(c * 72), 256, 0, stream>>>(Qb, Kb, Sb);
        gemm2_kernel<<<dim3(2, 16, c), 256, 0, stream>>>(Sb, Vt, Out, bh0);
    }
}

// Round 7
// 774.213 us; speedup vs baseline: 1.4020x; 1.0023x over previous
//
#include <hip/hip_runtime.h>
#include <hip/hip_bf16.h>

#define B_ 2
#define H_ 4
#define T_ 2048
#define NH_ 8192
#define D_ 256

typedef __attribute__((ext_vector_type(4))) float f32x4;
typedef __attribute__((ext_vector_type(8))) short bf16x8;
typedef __attribute__((ext_vector_type(4))) int i32x4;

__device__ __forceinline__ unsigned short f2bf(float f) {
    union { float f; unsigned u; } v;
    v.f = f;
    unsigned u = v.u;
    unsigned r = u + 0x7FFFu + ((u >> 16) & 1u);   // RNE
    return (unsigned short)(r >> 16);
}

// ---------------------------------------------------------------------------
// Kernel 1: RoPE + cast to bf16 for Q and K  (HBM-bound ~240 us: at ceiling)
// freq[pair p] = 2^(-p/256) / (2*pi)   (theta=2^16, NH=8192 exactly)
// ---------------------------------------------------------------------------
__global__ __launch_bounds__(256) void rope_cast_kernel(
    const float* __restrict__ Q, const float* __restrict__ K,
    unsigned short* __restrict__ Qb, unsigned short* __restrict__ Kb,
    int bh0)
{
    const long gid = (long)blockIdx.x * 256 + threadIdx.x;  // one 8-elem group
    const int ng = NH_ / 8;
    const int n8 = (int)(gid % ng) * 8;
    const long row = gid / ng;              // lbh*T + t
    const int t = (int)(row % T_);
    const int lbh = (int)(row / T_);

    const long in_off  = ((long)(bh0 + lbh) * T_ + t) * NH_ + n8;
    const long out_off = ((long)lbh * T_ + t) * NH_ + n8;

    float4 qa = *(const float4*)(Q + in_off);
    float4 qb4 = *(const float4*)(Q + in_off + 4);
    float4 ka = *(const float4*)(K + in_off);
    float4 kb4 = *(const float4*)(K + in_off + 4);
    float qv[8] = {qa.x, qa.y, qa.z, qa.w, qb4.x, qb4.y, qb4.z, qb4.w};
    float kv[8] = {ka.x, ka.y, ka.z, ka.w, kb4.x, kb4.y, kb4.z, kb4.w};

    union { i32x4 v; unsigned short u[8]; } qo, ko;
    const int p0 = n8 >> 1;
    const float tf = (float)t;
#pragma unroll
    for (int j = 0; j < 4; ++j) {
        float freq = exp2f(-(float)(p0 + j) * (1.0f / 256.0f)) * 0.15915494309189535f;
        float phase = tf * freq;
        float r = phase - floorf(phase);
        float ph = r * 6.283185307179586f;
        float c = __cosf(ph);
        float s = __sinf(ph);
        float qe = qv[2 * j], qodd = qv[2 * j + 1];
        float ke = kv[2 * j], kodd = kv[2 * j + 1];
        qo.u[2 * j]     = f2bf(qe * c - qodd * s);
        qo.u[2 * j + 1] = f2bf(qodd * c + qe * s);
        ko.u[2 * j]     = f2bf(ke * c - kodd * s);
        ko.u[2 * j + 1] = f2bf(kodd * c + ke * s);
    }
    *(i32x4*)(Qb + out_off) = qo.v;
    *(i32x4*)(Kb + out_off) = ko.v;
}

// ---------------------------------------------------------------------------
// Kernel 2: V [B,T,D] fp32 -> Vt [B,D,T] bf16 (transposed cast, LDS tiled)
// ---------------------------------------------------------------------------
__global__ __launch_bounds__(256) void vcast_kernel(
    const float* __restrict__ V, unsigned short* __restrict__ Vt)
{
    __shared__ unsigned short tile[64][72];
    const int t0 = blockIdx.x * 64;
    const int d0 = blockIdx.y * 64;
    const int b = blockIdx.z;
    const int tid = threadIdx.x;
#pragma unroll
    for (int rr = 0; rr < 16; ++rr) {
        int tl = rr * 4 + (tid >> 6);
        int dl = tid & 63;
        float v = V[((long)b * T_ + (t0 + tl)) * D_ + d0 + dl];
        tile[dl][tl] = f2bf(v);
    }
    __syncthreads();
#pragma unroll
    for (int rr = 0; rr < 16; ++rr) {
        int dl = rr * 4 + (tid >> 6);
        int tl = tid & 63;
        Vt[((long)b * D_ + (d0 + dl)) * T_ + t0 + tl] = tile[dl][tl];
    }
}

// ---------------------------------------------------------------------------
// gemm1: S = mask(Qr . Kr^T).  BM=256 x BN=128, BK=32, EIGHT waves (64x64
// each), 512 threads, triple-buffered LDS (72 KiB -> 2 blocks/CU = 16
// waves/CU = 4 waves/SIMD for latency hiding), counted vmcnt(3), both-sides
// XOR swizzle (0-conflict verified R2-R6), setprio, causal grid + XCD swizzle.
// VGPR must stay <= 128 for 4 waves/SIMD: acc 64 + operands ~32 + addr ~20.
// Race-safety identical to R5/R6: stage targets buf[t+2]; end-of-step barrier
// follows all waves' vmcnt(3) (tile t+1 landed) and their reads of buf[t].
// ---------------------------------------------------------------------------
#define GLD16(g, l) __builtin_amdgcn_global_load_lds(                         \
    (const __attribute__((address_space(1))) void*)(g),                       \
    (__attribute__((address_space(3))) void*)(l), 16, 0, 0)

#define STEP(RB, SB, t_, DO_STAGE, VMN) {                                     \
    bf16x8 af[4], bv[4];                                                      \
    _Pragma("unroll") for (int n = 0; n < 4; ++n)                             \
        bv[n] = *(const bf16x8*)&Bs[RB][wc * 64 + n * 16 + rofs][sl8];        \
    _Pragma("unroll") for (int m = 0; m < 4; ++m)                             \
        af[m] = *(const bf16x8*)&As[RB][wr * 64 + m * 16 + rofs][sl8];        \
    if (DO_STAGE) {                                                           \
        const long ko_ = (long)((t_) + 2) * 32;                               \
        GLD16(gA0 + ko_, &As[SB][0][0] + dst);                                \
        GLD16(gA1 + ko_, &As[SB][128][0] + dst);                              \
        GLD16(gB0 + ko_, &Bs[SB][0][0] + dst);                                \
    }                                                                         \
    __builtin_amdgcn_s_setprio(1);                                            \
    _Pragma("unroll") for (int m = 0; m < 4; ++m)                             \
        _Pragma("unroll") for (int n = 0; n < 4; ++n)                         \
            acc[m][n] = __builtin_amdgcn_mfma_f32_16x16x32_bf16(              \
                af[m], bv[n], acc[m][n], 0, 0, 0);                            \
    __builtin_amdgcn_s_setprio(0);                                            \
    if ((VMN) == 3)      asm volatile("s_waitcnt vmcnt(3)" ::: "memory");     \
    else if ((VMN) == 0) asm volatile("s_waitcnt vmcnt(0)" ::: "memory");     \
    if ((VMN) >= 0) { __builtin_amdgcn_s_barrier();                           \
                      __builtin_amdgcn_sched_barrier(0); }                    \
}

__global__ __launch_bounds__(512, 4) void gemm1_kernel(
    const unsigned short* __restrict__ Qb, const unsigned short* __restrict__ Kb,
    unsigned short* __restrict__ S)
{
    __shared__ __align__(16) unsigned short As[3][256][32];   // 48 KiB
    __shared__ __align__(16) unsigned short Bs[3][128][32];   // 24 KiB

    // XCD swizzle (grid = 576, divisible by 8 -> simple bijective form)
    const int nwg = gridDim.x;
    const int orig = blockIdx.x;
    const int wg = (orig & 7) * (nwg >> 3) + (orig >> 3);

    // causal tile decode: per bh, row-tiles i (256 rows), col-tiles j (128
    // cols), j <= 2i+1.  base(i) = i*i+i, count 2i+2, 72 tiles per bh.
    const int t72 = wg % 72;
    const int lbh = wg / 72;
    int it = (int)((sqrtf(4.0f * (float)t72 + 1.0f) - 1.0f) * 0.5f);
    while ((it + 1) * (it + 2) <= t72) ++it;
    while (it * (it + 1) > t72) --it;
    const int jt = t72 - it * (it + 1);

    const int tid = threadIdx.x;
    const int lane = tid & 63;
    const int wid = tid >> 6;                // 0..7
    const int wr = wid >> 1;                 // 0..3 (64-row group)
    const int wc = wid & 1;                  // 0..1 (64-col half)
    const int rofs = lane & 15;
    // read-side swizzled 8-elem chunk (XOR involution, verified 0-conflict)
    const int sl8 = (((lane >> 4) ^ ((lane >> 1) & 3))) << 3;

    // stage addressing: dest linear (rule 21), source pre-swizzled.
    // 512 threads: rows tid>>2 (0..127) per call, 4 threads x 8 elems per row.
    const int ss8 = (((tid & 3) ^ ((tid >> 3) & 3))) << 3;
    const int dst = tid * 8;                 // elems within one [128][32] chunk
    const unsigned short* Ab = Qb + (long)lbh * T_ * NH_ + (long)it * 256 * NH_;
    const unsigned short* Bb = Kb + (long)lbh * T_ * NH_ + (long)jt * 128 * NH_;
    const unsigned short* gA0 = Ab + (long)(tid >> 2) * NH_ + ss8;
    const unsigned short* gA1 = gA0 + 128L * NH_;
    const unsigned short* gB0 = Bb + (long)(tid >> 2) * NH_ + ss8;

    f32x4 acc[4][4];
#pragma unroll
    for (int m = 0; m < 4; ++m)
#pragma unroll
        for (int n = 0; n < 4; ++n)
            acc[m][n] = (f32x4){0.f, 0.f, 0.f, 0.f};

    // prologue: tiles 0,1 in flight (6 loads/wave); wait for tile 0 only
    {
        GLD16(gA0, &As[0][0][0] + dst);
        GLD16(gA1, &As[0][128][0] + dst);
        GLD16(gB0, &Bs[0][0][0] + dst);
        GLD16(gA0 + 32, &As[1][0][0] + dst);
        GLD16(gA1 + 32, &As[1][128][0] + dst);
        GLD16(gB0 + 32, &Bs[1][0][0] + dst);
    }
    asm volatile("s_waitcnt vmcnt(3)" ::: "memory");
    __builtin_amdgcn_s_barrier();
    __builtin_amdgcn_sched_barrier(0);

#pragma unroll 1
    for (int t = 0; t < 252; t += 3) {
        STEP(0, 2, t,     true, 3)
        STEP(1, 0, t + 1, true, 3)
        STEP(2, 1, t + 2, true, 3)
    }
    STEP(0, 2, 252, true, 3)
    STEP(1, 0, 253, true, 3)
    STEP(2, 1, 254, false, 0)
    STEP(0, 0, 255, false, -1)

    // epilogue: strict-lower mask, bf16 store
    unsigned short* Sp = S + (long)lbh * T_ * T_;
    const int r0 = it * 256 + wr * 64 + ((lane >> 4) << 2);
    const int c0 = jt * 128 + wc * 64 + (lane & 15);
#pragma unroll
    for (int m = 0; m < 4; ++m) {
#pragma unroll
        for (int i = 0; i < 4; ++i) {
            const int rr = r0 + m * 16 + i;
#pragma unroll
            for (int n = 0; n < 4; ++n) {
                const int cc = c0 + n * 16;
                float v = (cc < rr) ? acc[m][n][i] : 0.0f;
                Sp[(long)rr * T_ + cc] = f2bf(v);
            }
        }
    }
}

// ---------------------------------------------------------------------------
// gemm2 support (m97 structure, 128x128): O = S . V
// ---------------------------------------------------------------------------
__device__ __forceinline__ void stage_tile(const unsigned short* g, long ldk,
                                           unsigned short* l, int tid)
{
    const int row = tid >> 2;            // 0..63
    const int col = (tid & 3) << 3;      // 0,8,16,24
    const unsigned short* g0 = g + (long)row * ldk + col;
    const unsigned short* g1 = g0 + 64 * ldk;
    unsigned short* l0 = l + tid * 8;
    unsigned short* l1 = l0 + 2048;      // rows 64..127
    GLD16(g0, l0);
    GLD16(g1, l1);
}

__global__ __launch_bounds__(256) void gemm2_kernel(
    const unsigned short* __restrict__ S, const unsigned short* __restrict__ Vt,
    float* __restrict__ Out, int bh0)
{
    const int jn = blockIdx.x;
    const int it = blockIdx.y;
    const int lbh = blockIdx.z;
    const int bh = bh0 + lbh;
    const int b = bh / H_;

    __shared__ __align__(16) unsigned short As2[2][128][32];
    __shared__ __align__(16) unsigned short Bs2[2][128][32];

    const unsigned short* A  = S + (long)lbh * T_ * T_ + (long)it * 128 * T_;
    const unsigned short* Bm = Vt + (long)b * D_ * T_ + (long)jn * 128 * T_;
    const int KT = (it + 1) * 4;   // causal: K runs to end of diagonal tile

    const int tid = threadIdx.x;
    const int lane = tid & 63;
    const int wid = tid >> 6;
    const int wr = wid >> 1;
    const int wc = wid & 1;
    f32x4 acc[4][4];
#pragma unroll
    for (int m = 0; m < 4; ++m)
#pragma unroll
        for (int n = 0; n < 4; ++n)
            acc[m][n] = (f32x4){0.f, 0.f, 0.f, 0.f};
    const int rofs = lane & 15;
    const int kofs = (lane >> 4) * 8;
    stage_tile(A, T_, &As2[0][0][0], tid);
    stage_tile(Bm, T_, &Bs2[0][0][0], tid);
    int cur = 0;
    for (int kt = 0; kt < KT; ++kt) {
        __syncthreads();
        if (kt + 1 < KT) {
            stage_tile(A + (long)(kt + 1) * 32, T_, &As2[cur ^ 1][0][0], tid);
            stage_tile(Bm + (long)(kt + 1) * 32, T_, &Bs2[cur ^ 1][0][0], tid);
        }
        bf16x8 af[4], bfr[4];
#pragma unroll
        for (int m = 0; m < 4; ++m)
            af[m] = *(const bf16x8*)&As2[cur][wr * 64 + m * 16 + rofs][kofs];
#pragma unroll
        for (int n = 0; n < 4; ++n)
            bfr[n] = *(const bf16x8*)&Bs2[cur][wc * 64 + n * 16 + rofs][kofs];
#pragma unroll
        for (int m = 0; m < 4; ++m)
#pragma unroll
            for (int n = 0; n < 4; ++n)
                acc[m][n] = __builtin_amdgcn_mfma_f32_16x16x32_bf16(
                    af[m], bfr[n], acc[m][n], 0, 0, 0);
        cur ^= 1;
    }

    float* Op = Out + ((long)bh * T_ + it * 128) * D_ + jn * 128;
#pragma unroll
    for (int m = 0; m < 4; ++m) {
        const int rbase = wr * 64 + m * 16 + ((lane >> 4) << 2);
#pragma unroll
        for (int i = 0; i < 4; ++i) {
            const int rr = rbase + i;
#pragma unroll
            for (int n = 0; n < 4; ++n) {
                const int cc = wc * 64 + n * 16 + (lane & 15);
                Op[(long)rr * D_ + cc] = acc[m][n][i];
            }
        }
    }
}

// ---------------------------------------------------------------------------
extern "C" void kernel_launch(void* const* d_in, const int* in_sizes, int n_in,
                              void* d_out, int out_size, void* d_ws, size_t ws_size,
                              hipStream_t stream)
{
    const float* Q = (const float*)d_in[0];
    const float* K = (const float*)d_in[1];
    const float* V = (const float*)d_in[2];
    float* Out = (float*)d_out;

    const size_t vt_elems = (size_t)B_ * D_ * T_;                 // bf16
    auto need = [&](int c) {
        return 2 * vt_elems + (size_t)c * T_ * NH_ * 2 * 2        // Qb+Kb bytes
             + (size_t)c * T_ * T_ * 2;                           // S bytes
    };
    int c;
    if      (ws_size >= need(8)) c = 8;
    else if (ws_size >= need(4)) c = 4;
    else if (ws_size >= need(2)) c = 2;
    else if (ws_size >= need(1)) c = 1;
    else return;

    unsigned short* Vt = (unsigned short*)d_ws;
    unsigned short* Qb = Vt + vt_elems;
    unsigned short* Kb = Qb + (size_t)c * T_ * NH_;
    unsigned short* Sb = Kb + (size_t)c * T_ * NH_;

    vcast_kernel<<<dim3(T_ / 64, D_ / 64, B_), 256, 0, stream>>>(V, Vt);

    for (int bh0 = 0; bh0 < B_ * H_; bh0 += c) {
        const long groups = (long)c * T_ * (NH_ / 8);
        rope_cast_kernel<<<(int)(groups / 256), 256, 0, stream>>>(Q, K, Qb, Kb, bh0);
        gemm1_kernel<<<dim3(c * 72), 512, 0, stream>>>(Qb, Kb, Sb);
        gemm2_kernel<<<dim3(2, 16, c), 256, 0, stream>>>(Sb, Vt, Out, bh0);
    }
}

// Round 8
// 672.079 us; speedup vs baseline: 1.6150x; 1.1520x over previous
//
#include <hip/hip_runtime.h>
#include <hip/hip_bf16.h>

#define B_ 2
#define H_ 4
#define T_ 2048
#define NH_ 8192
#define D_ 256

typedef __attribute__((ext_vector_type(4))) float f32x4;
typedef __attribute__((ext_vector_type(8))) short bf16x8;
typedef __attribute__((ext_vector_type(4))) int i32x4;

__device__ __forceinline__ unsigned short f2bf(float f) {
    union { float f; unsigned u; } v;
    v.f = f;
    unsigned u = v.u;
    unsigned r = u + 0x7FFFu + ((u >> 16) & 1u);   // RNE
    return (unsigned short)(r >> 16);
}

// ---------------------------------------------------------------------------
// Kernel 1: RoPE + cast to bf16 for Q and K  (HBM-bound ~240 us: at ceiling)
// ---------------------------------------------------------------------------
__global__ __launch_bounds__(256) void rope_cast_kernel(
    const float* __restrict__ Q, const float* __restrict__ K,
    unsigned short* __restrict__ Qb, unsigned short* __restrict__ Kb,
    int bh0)
{
    const long gid = (long)blockIdx.x * 256 + threadIdx.x;  // one 8-elem group
    const int ng = NH_ / 8;
    const int n8 = (int)(gid % ng) * 8;
    const long row = gid / ng;              // lbh*T + t
    const int t = (int)(row % T_);
    const int lbh = (int)(row / T_);

    const long in_off  = ((long)(bh0 + lbh) * T_ + t) * NH_ + n8;
    const long out_off = ((long)lbh * T_ + t) * NH_ + n8;

    float4 qa = *(const float4*)(Q + in_off);
    float4 qb4 = *(const float4*)(Q + in_off + 4);
    float4 ka = *(const float4*)(K + in_off);
    float4 kb4 = *(const float4*)(K + in_off + 4);
    float qv[8] = {qa.x, qa.y, qa.z, qa.w, qb4.x, qb4.y, qb4.z, qb4.w};
    float kv[8] = {ka.x, ka.y, ka.z, ka.w, kb4.x, kb4.y, kb4.z, kb4.w};

    union { i32x4 v; unsigned short u[8]; } qo, ko;
    const int p0 = n8 >> 1;
    const float tf = (float)t;
#pragma unroll
    for (int j = 0; j < 4; ++j) {
        float freq = exp2f(-(float)(p0 + j) * (1.0f / 256.0f)) * 0.15915494309189535f;
        float phase = tf * freq;
        float r = phase - floorf(phase);
        float ph = r * 6.283185307179586f;
        float c = __cosf(ph);
        float s = __sinf(ph);
        float qe = qv[2 * j], qodd = qv[2 * j + 1];
        float ke = kv[2 * j], kodd = kv[2 * j + 1];
        qo.u[2 * j]     = f2bf(qe * c - qodd * s);
        qo.u[2 * j + 1] = f2bf(qodd * c + qe * s);
        ko.u[2 * j]     = f2bf(ke * c - kodd * s);
        ko.u[2 * j + 1] = f2bf(kodd * c + ke * s);
    }
    *(i32x4*)(Qb + out_off) = qo.v;
    *(i32x4*)(Kb + out_off) = ko.v;
}

// ---------------------------------------------------------------------------
// Kernel 2: V [B,T,D] fp32 -> Vt [B,D,T] bf16 (transposed cast, LDS tiled)
// ---------------------------------------------------------------------------
__global__ __launch_bounds__(256) void vcast_kernel(
    const float* __restrict__ V, unsigned short* __restrict__ Vt)
{
    __shared__ unsigned short tile[64][72];
    const int t0 = blockIdx.x * 64;
    const int d0 = blockIdx.y * 64;
    const int b = blockIdx.z;
    const int tid = threadIdx.x;
#pragma unroll
    for (int rr = 0; rr < 16; ++rr) {
        int tl = rr * 4 + (tid >> 6);
        int dl = tid & 63;
        float v = V[((long)b * T_ + (t0 + tl)) * D_ + d0 + dl];
        tile[dl][tl] = f2bf(v);
    }
    __syncthreads();
#pragma unroll
    for (int rr = 0; rr < 16; ++rr) {
        int dl = rr * 4 + (tid >> 6);
        int tl = tid & 63;
        Vt[((long)b * D_ + (d0 + dl)) * T_ + t0 + tl] = tile[dl][tl];
    }
}

// ---------------------------------------------------------------------------
// gemm1: S = mask(Qr . Kr^T).  BM=BN=256 (HALVES L3 panel traffic vs 256x128:
// the measured 8 TB/s fabric ceiling was the R4-R7 invariant), BK=32, 8 waves
// (128x64 wave tiles), triple-buffered 96 KiB LDS (1 block/CU), counted
// vmcnt(4), both-sides XOR swizzle (0-conflict verified), setprio.
// PACKING FIX: wg < nFull are full-K tiles (1/CU); the last 32 tiles are
// split into 8 K-chunks each (wg >= nFull), writing f32 partials to ws;
// reduce_kernel sums, masks, casts.  Every CU gets ~1 full + ~1 chunk job.
// ---------------------------------------------------------------------------
#define GLD16(g, l) __builtin_amdgcn_global_load_lds(                         \
    (const __attribute__((address_space(1))) void*)(g),                       \
    (__attribute__((address_space(3))) void*)(l), 16, 0, 0)

__global__ __launch_bounds__(512, 2) void gemm1_kernel(
    const unsigned short* __restrict__ Qb, const unsigned short* __restrict__ Kb,
    unsigned short* __restrict__ S, float* __restrict__ part, int nFull)
{
    __shared__ __align__(16) unsigned short As[3][256][32];   // 48 KiB
    __shared__ __align__(16) unsigned short Bs[3][256][32];   // 48 KiB

    const int wg = blockIdx.x;
    int tileIdx, KT, kc;
    bool full;
    if (wg < nFull) {
        // bijective XCD swizzle (m204 variant, works for any nFull)
        const int xcd = wg & 7, q8 = nFull >> 3, r8 = nFull & 7;
        tileIdx = (xcd < r8 ? xcd * (q8 + 1) : r8 * (q8 + 1) + (xcd - r8) * q8)
                + (wg >> 3);
        KT = 256; kc = 0; full = true;
    } else {
        const int j = wg - nFull;
        tileIdx = nFull + (j >> 3);
        kc = j & 7;
        KT = 32; full = false;               // K-chunk of 1024
    }
    const int lbh = tileIdx / 36;
    const int t36 = tileIdx % 36;
    int it = (int)((sqrtf(8.0f * (float)t36 + 1.0f) - 1.0f) * 0.5f);
    if ((it + 1) * (it + 2) / 2 <= t36) ++it;
    if (it * (it + 1) / 2 > t36) --it;
    const int jt = t36 - it * (it + 1) / 2;

    const int tid = threadIdx.x;
    const int lane = tid & 63;
    const int wid = tid >> 6;                // 0..7
    const int wr = wid >> 2;                 // 0..1 (128-row half)
    const int wc = wid & 3;                  // 0..3 (64-col quarter)
    const int rofs = lane & 15;
    const int sl8 = (((lane >> 4) ^ ((lane >> 1) & 3))) << 3;  // read swizzle

    // staging: 512 threads, 4 GLD16 each per K-tile (A 16KB + B 16KB)
    const int ss8 = (((tid & 3) ^ ((tid >> 3) & 3))) << 3;     // src pre-swizzle
    const int dst = tid * 8;                 // elems within one [128][32] half
    const long K0 = (long)kc * 1024;
    const unsigned short* Ab = Qb + (long)lbh * T_ * NH_ + (long)it * 256 * NH_ + K0;
    const unsigned short* Bb = Kb + (long)lbh * T_ * NH_ + (long)jt * 256 * NH_ + K0;
    const unsigned short* gA0 = Ab + (long)(tid >> 2) * NH_ + ss8;
    const unsigned short* gA1 = gA0 + 128L * NH_;
    const unsigned short* gB0 = Bb + (long)(tid >> 2) * NH_ + ss8;
    const unsigned short* gB1 = gB0 + 128L * NH_;
    unsigned short* AsB = &As[0][0][0];
    unsigned short* BsB = &Bs[0][0][0];

    f32x4 acc[8][4];
#pragma unroll
    for (int m = 0; m < 8; ++m)
#pragma unroll
        for (int n = 0; n < 4; ++n)
            acc[m][n] = (f32x4){0.f, 0.f, 0.f, 0.f};

#define G256_STAGE(SB, kt) {                                                  \
    const long ko_ = (long)(kt) * 32;                                         \
    GLD16(gA0 + ko_, AsB + (SB) * 8192 + dst);                                \
    GLD16(gA1 + ko_, AsB + (SB) * 8192 + 4096 + dst);                         \
    GLD16(gB0 + ko_, BsB + (SB) * 8192 + dst);                                \
    GLD16(gB1 + ko_, BsB + (SB) * 8192 + 4096 + dst); }

    // prologue: tiles 0,1 in flight (8 loads); wait for tile 0 only
    G256_STAGE(0, 0)
    G256_STAGE(1, 1)
    asm volatile("s_waitcnt vmcnt(4)" ::: "memory");
    __builtin_amdgcn_s_barrier();
    __builtin_amdgcn_sched_barrier(0);

    const int arow = wr * 128 + rofs;
    const int brow = wc * 64 + rofs;
#pragma unroll 1
    for (int t = 0; t < KT; ++t) {
        const int rb = t % 3;
        bf16x8 af[8], bv[4];
        const unsigned short* ab = AsB + rb * 8192 + sl8;
        const unsigned short* bb = BsB + rb * 8192 + sl8;
#pragma unroll
        for (int n = 0; n < 4; ++n)
            bv[n] = *(const bf16x8*)(bb + (brow + n * 16) * 32);
#pragma unroll
        for (int m = 0; m < 8; ++m)
            af[m] = *(const bf16x8*)(ab + (arow + m * 16) * 32);
        if (t + 2 < KT) { const int sb = (t + 2) % 3; G256_STAGE(sb, t + 2) }
        __builtin_amdgcn_s_setprio(1);
#pragma unroll
        for (int m = 0; m < 8; ++m)
#pragma unroll
            for (int n = 0; n < 4; ++n)
                acc[m][n] = __builtin_amdgcn_mfma_f32_16x16x32_bf16(
                    af[m], bv[n], acc[m][n], 0, 0, 0);
        __builtin_amdgcn_s_setprio(0);
        if (t < KT - 2) {
            asm volatile("s_waitcnt vmcnt(4)" ::: "memory");
            __builtin_amdgcn_s_barrier();
            __builtin_amdgcn_sched_barrier(0);
        } else if (t == KT - 2) {
            asm volatile("s_waitcnt vmcnt(0)" ::: "memory");
            __builtin_amdgcn_s_barrier();
            __builtin_amdgcn_sched_barrier(0);
        }
    }

    if (full) {
        // strict-lower mask, bf16 store
        unsigned short* Sp = S + (long)lbh * T_ * T_;
        const int r0 = it * 256 + wr * 128 + ((lane >> 4) << 2);
        const int c0 = jt * 256 + wc * 64 + (lane & 15);
#pragma unroll
        for (int m = 0; m < 8; ++m) {
#pragma unroll
            for (int i = 0; i < 4; ++i) {
                const int rr = r0 + m * 16 + i;
#pragma unroll
                for (int n = 0; n < 4; ++n) {
                    const int cc = c0 + n * 16;
                    float v = (cc < rr) ? acc[m][n][i] : 0.0f;
                    Sp[(long)rr * T_ + cc] = f2bf(v);
                }
            }
        }
    } else {
        // raw f32 partial: part[(q*8+kc)][256][256]
        const int q = tileIdx - nFull;
        float* Pp = part + ((long)(q * 8 + kc)) * 65536;
        const int r0 = wr * 128 + ((lane >> 4) << 2);
        const int c0 = wc * 64 + (lane & 15);
#pragma unroll
        for (int m = 0; m < 8; ++m) {
#pragma unroll
            for (int i = 0; i < 4; ++i) {
                const int rr = r0 + m * 16 + i;
#pragma unroll
                for (int n = 0; n < 4; ++n)
                    Pp[rr * 256 + c0 + n * 16] = acc[m][n][i];
            }
        }
    }
#undef G256_STAGE
}

// ---------------------------------------------------------------------------
// reduce: sum 8 K-chunk partials, strict-lower mask, cast, store to S.
// grid: 32 tiles x 64 blocks; 256 thr x 4 elems.
// ---------------------------------------------------------------------------
__global__ __launch_bounds__(256) void reduce_kernel(
    const float* __restrict__ part, unsigned short* __restrict__ S, int nFull)
{
    const int b = blockIdx.x;
    const int q = b >> 6;
    const int e0 = (b & 63) * 1024 + threadIdx.x * 4;
    const int tileIdx = nFull + q;
    const int lbh = tileIdx / 36;
    const int t36 = tileIdx % 36;
    int it = (int)((sqrtf(8.0f * (float)t36 + 1.0f) - 1.0f) * 0.5f);
    if ((it + 1) * (it + 2) / 2 <= t36) ++it;
    if (it * (it + 1) / 2 > t36) --it;
    const int jt = t36 - it * (it + 1) / 2;

    float4 s = {0.f, 0.f, 0.f, 0.f};
#pragma unroll
    for (int kc = 0; kc < 8; ++kc) {
        float4 p = *(const float4*)(part + ((long)(q * 8 + kc)) * 65536 + e0);
        s.x += p.x; s.y += p.y; s.z += p.z; s.w += p.w;
    }
    const int row = e0 >> 8;
    const int col = e0 & 255;
    const int rr = it * 256 + row;
    const int c0 = jt * 256 + col;
    unsigned short o[4];
#pragma unroll
    for (int k = 0; k < 4; ++k) {
        float v = ((c0 + k) < rr) ? ((const float*)&s)[k] : 0.0f;
        o[k] = f2bf(v);
    }
    *(i32x4*)0;  // (unused; keep type header consistent)
    unsigned short* Sp = S + (long)lbh * T_ * T_ + (long)rr * T_ + c0;
    Sp[0] = o[0]; Sp[1] = o[1]; Sp[2] = o[2]; Sp[3] = o[3];
}

// ---------------------------------------------------------------------------
// gemm2 (m97 structure, 128x128): O = S . V
// ---------------------------------------------------------------------------
__device__ __forceinline__ void stage_tile(const unsigned short* g, long ldk,
                                           unsigned short* l, int tid)
{
    const int row = tid >> 2;
    const int col = (tid & 3) << 3;
    const unsigned short* g0 = g + (long)row * ldk + col;
    const unsigned short* g1 = g0 + 64 * ldk;
    unsigned short* l0 = l + tid * 8;
    unsigned short* l1 = l0 + 2048;
    GLD16(g0, l0);
    GLD16(g1, l1);
}

__global__ __launch_bounds__(256) void gemm2_kernel(
    const unsigned short* __restrict__ S, const unsigned short* __restrict__ Vt,
    float* __restrict__ Out, int bh0)
{
    const int jn = blockIdx.x;
    const int it = blockIdx.y;
    const int lbh = blockIdx.z;
    const int bh = bh0 + lbh;
    const int b = bh / H_;

    __shared__ __align__(16) unsigned short As2[2][128][32];
    __shared__ __align__(16) unsigned short Bs2[2][128][32];

    const unsigned short* A  = S + (long)lbh * T_ * T_ + (long)it * 128 * T_;
    const unsigned short* Bm = Vt + (long)b * D_ * T_ + (long)jn * 128 * T_;
    const int KT = (it + 1) * 4;

    const int tid = threadIdx.x;
    const int lane = tid & 63;
    const int wid = tid >> 6;
    const int wr = wid >> 1;
    const int wc = wid & 1;
    f32x4 acc[4][4];
#pragma unroll
    for (int m = 0; m < 4; ++m)
#pragma unroll
        for (int n = 0; n < 4; ++n)
            acc[m][n] = (f32x4){0.f, 0.f, 0.f, 0.f};
    const int rofs = lane & 15;
    const int kofs = (lane >> 4) * 8;
    stage_tile(A, T_, &As2[0][0][0], tid);
    stage_tile(Bm, T_, &Bs2[0][0][0], tid);
    int cur = 0;
    for (int kt = 0; kt < KT; ++kt) {
        __syncthreads();
        if (kt + 1 < KT) {
            stage_tile(A + (long)(kt + 1) * 32, T_, &As2[cur ^ 1][0][0], tid);
            stage_tile(Bm + (long)(kt + 1) * 32, T_, &Bs2[cur ^ 1][0][0], tid);
        }
        bf16x8 af[4], bfr[4];
#pragma unroll
        for (int m = 0; m < 4; ++m)
            af[m] = *(const bf16x8*)&As2[cur][wr * 64 + m * 16 + rofs][kofs];
#pragma unroll
        for (int n = 0; n < 4; ++n)
            bfr[n] = *(const bf16x8*)&Bs2[cur][wc * 64 + n * 16 + rofs][kofs];
#pragma unroll
        for (int m = 0; m < 4; ++m)
#pragma unroll
            for (int n = 0; n < 4; ++n)
                acc[m][n] = __builtin_amdgcn_mfma_f32_16x16x32_bf16(
                    af[m], bfr[n], acc[m][n], 0, 0, 0);
        cur ^= 1;
    }

    float* Op = Out + ((long)bh * T_ + it * 128) * D_ + jn * 128;
#pragma unroll
    for (int m = 0; m < 4; ++m) {
        const int rbase = wr * 64 + m * 16 + ((lane >> 4) << 2);
#pragma unroll
        for (int i = 0; i < 4; ++i) {
            const int rr = rbase + i;
#pragma unroll
            for (int n = 0; n < 4; ++n) {
                const int cc = wc * 64 + n * 16 + (lane & 15);
                Op[(long)rr * D_ + cc] = acc[m][n][i];
            }
        }
    }
}

// ---------------------------------------------------------------------------
extern "C" void kernel_launch(void* const* d_in, const int* in_sizes, int n_in,
                              void* d_out, int out_size, void* d_ws, size_t ws_size,
                              hipStream_t stream)
{
    const float* Q = (const float*)d_in[0];
    const float* K = (const float*)d_in[1];
    const float* V = (const float*)d_in[2];
    float* Out = (float*)d_out;

    const size_t vt_elems = (size_t)B_ * D_ * T_;                 // bf16
    const size_t part_bytes = 256ull * 65536ull * 4ull;           // 67 MB
    auto need = [&](int c, bool split) {
        return 2 * vt_elems + (size_t)c * T_ * NH_ * 2 * 2        // Qb+Kb bytes
             + (size_t)c * T_ * T_ * 2                            // S bytes
             + (split ? part_bytes : 0);
    };
    int c; bool split;
    if      (ws_size >= need(8, true))  { c = 8; split = true; }
    else if (ws_size >= need(8, false)) { c = 8; split = false; }
    else if (ws_size >= need(4, false)) { c = 4; split = false; }
    else if (ws_size >= need(2, false)) { c = 2; split = false; }
    else if (ws_size >= need(1, false)) { c = 1; split = false; }
    else return;

    unsigned short* Vt = (unsigned short*)d_ws;
    unsigned short* Qb = Vt + vt_elems;
    unsigned short* Kb = Qb + (size_t)c * T_ * NH_;
    unsigned short* Sb = Kb + (size_t)c * T_ * NH_;
    float* part = (float*)(Sb + (size_t)c * T_ * T_);

    vcast_kernel<<<dim3(T_ / 64, D_ / 64, B_), 256, 0, stream>>>(V, Vt);

    for (int bh0 = 0; bh0 < B_ * H_; bh0 += c) {
        const long groups = (long)c * T_ * (NH_ / 8);
        rope_cast_kernel<<<(int)(groups / 256), 256, 0, stream>>>(Q, K, Qb, Kb, bh0);
        const int nt = 36 * c;
        if (split) {
            const int nFull = nt - 32;                 // 256 when c=8
            gemm1_kernel<<<dim3(nFull + 256), 512, 0, stream>>>(Qb, Kb, Sb, part, nFull);
            reduce_kernel<<<dim3(32 * 64), 256, 0, stream>>>(part, Sb, nFull);
        } else {
            gemm1_kernel<<<dim3(nt), 512, 0, stream>>>(Qb, Kb, Sb, part, nt);
        }
        gemm2_kernel<<<dim3(2, 16, c), 256, 0, stream>>>(Sb, Vt, Out, bh0);
    }
}